// Round 16
// baseline (936.973 us; speedup 1.0000x reference)
//
#include <hip/hip_runtime.h>

typedef unsigned short ushort_t;
typedef _Float16 f16x8 __attribute__((ext_vector_type(8)));
typedef float f32x4 __attribute__((ext_vector_type(4)));
typedef float f32x2 __attribute__((ext_vector_type(2)));
typedef unsigned short us8 __attribute__((ext_vector_type(8)));

#define H_DIM 256
#define OUT_DIM 256

__device__ inline float lrelu(float v) { return v > 0.f ? v : 0.01f * v; }

__device__ inline unsigned short f2h(float f) {
    _Float16 h = (_Float16)f;
    unsigned short u;
    __builtin_memcpy(&u, &h, 2);
    return u;
}

__device__ inline float h2f(unsigned short u) {
    _Float16 h;
    __builtin_memcpy(&h, &u, 2);
    return (float)h;
}

// ---------- prep kernels ----------

__global__ void k_gather_x0(const float* __restrict__ sst, const int* __restrict__ mask,
                            float* __restrict__ x0, int NT, int Nn, int F) {
    int v = blockIdx.x * 256 + threadIdx.x;
    if (v < NT) {
        int b = v / Nn;
        int i = v - b * Nn;
        x0[v] = sst[(size_t)b * F + mask[i]];
    }
}

// count + record each edge's rank within its dst bucket (coalesced store)
__global__ void k_count(const int* __restrict__ dst, int* __restrict__ cnt,
                        int* __restrict__ rank, int E) {
    int e = blockIdx.x * 256 + threadIdx.x;
    if (e < E) rank[e] = atomicAdd(&cnt[dst[e]], 1);
}

__global__ void k_dis(const int* __restrict__ cnt, float* __restrict__ dis, int NT) {
    int v = blockIdx.x * 256 + threadIdx.x;
    if (v < NT) dis[v] = rsqrtf((float)cnt[v] + 1.0f);
}

__global__ void k_scan_block(const int* __restrict__ cnt, int* __restrict__ bsum, int NT) {
    __shared__ int s[256];
    int i = blockIdx.x * 256 + threadIdx.x;
    s[threadIdx.x] = (i < NT) ? cnt[i] : 0;
    __syncthreads();
    for (int o = 128; o > 0; o >>= 1) {
        if (threadIdx.x < o) s[threadIdx.x] += s[threadIdx.x + o];
        __syncthreads();
    }
    if (threadIdx.x == 0) bsum[blockIdx.x] = s[0];
}

__global__ void k_scan_top(const int* __restrict__ bsum, int* __restrict__ bpre, int nb) {
    __shared__ int s[512];
    int t = threadIdx.x;
    int v = (t < nb) ? bsum[t] : 0;
    s[t] = v;
    __syncthreads();
    for (int o = 1; o < nb; o <<= 1) {
        int add = (t >= o) ? s[t - o] : 0;
        __syncthreads();
        s[t] += add;
        __syncthreads();
    }
    if (t < nb) bpre[t] = s[t] - v;   // exclusive
}

__global__ void k_scan_scatter(const int* __restrict__ cnt, const int* __restrict__ bpre,
                               int* __restrict__ startp, int NT) {
    __shared__ int s[256];
    int t = threadIdx.x;
    int i = blockIdx.x * 256 + t;
    int v = (i < NT) ? cnt[i] : 0;
    s[t] = v;
    __syncthreads();
    for (int o = 1; o < 256; o <<= 1) {
        int add = (t >= o) ? s[t - o] : 0;
        __syncthreads();
        s[t] += add;
        __syncthreads();
    }
    int excl = s[t] - v + bpre[blockIdx.x];
    if (i < NT) startp[i] = excl;
}

// fill: atomic-free; one packed 8B store per edge {src, cnorm bits}
__global__ void k_fill(const int* __restrict__ src, const int* __restrict__ dst,
                       const int* __restrict__ rank, const int* __restrict__ startp,
                       const float* __restrict__ dis, int2* __restrict__ ecsr, int E) {
    int e = blockIdx.x * 256 + threadIdx.x;
    if (e < E) {
        int s = src[e], d = dst[e];
        float nw = dis[s] * dis[d];
        int p = startp[d] + rank[e];
        ecsr[p] = make_int2(s, __float_as_int(nw));
    }
}

__global__ void k_prepW(const float* __restrict__ Ws, ushort_t* __restrict__ Wt, int total) {
    int idx = blockIdx.x * 256 + threadIdx.x;
    if (idx < total) {
        int l = idx >> 16;          // layer
        int rem = idx & 65535;
        int k = rem >> 8;           // input dim
        int n = rem & 255;          // output dim
        Wt[(l << 16) + (n << 8) + k] = f2h(Ws[idx]);
    }
}

// ---------- layer 1 (scalar input) ----------

__global__ void k_agg0(const float* __restrict__ x0, const int* __restrict__ startp,
                       const int* __restrict__ cnt, const int2* __restrict__ ecsr,
                       const float* __restrict__ dis, float* __restrict__ y0, int NT) {
    int v = blockIdx.x * 256 + threadIdx.x;
    if (v >= NT) return;
    float d = dis[v];
    float acc = d * d * x0[v];
    int s = startp[v], e = s + cnt[v];
    for (int i = s; i < e; i++) {
        int2 ec = ecsr[i];
        acc += __int_as_float(ec.y) * x0[ec.x];
    }
    y0[v] = acc;
}

__global__ void k_expand(const float* __restrict__ x0, const float* __restrict__ y0,
                         const float* __restrict__ W1, const float* __restrict__ b1,
                         ushort_t* __restrict__ xh, int NT) {
    int idx = blockIdx.x * 256 + threadIdx.x;      // one float4-worth each, NT*64 total
    int v = idx >> 6;
    int q = idx & 63;
    if (v >= NT) return;
    float xv = x0[v], yv = y0[v];
    float4 w = ((const float4*)W1)[q];
    float4 b = ((const float4*)b1)[q];
    ushort4 o;
    o.x = f2h(xv + lrelu(yv * w.x + b.x));
    o.y = f2h(xv + lrelu(yv * w.y + b.y));
    o.z = f2h(xv + lrelu(yv * w.z + b.z));
    o.w = f2h(xv + lrelu(yv * w.w + b.w));
    ((ushort4*)xh)[(size_t)v * 64 + q] = o;
}

// ---------- GEMM: z = xh @ W (fp16 MFMA, f32 acc, fp8 e4m3 out) ----------
// W held in REGISTERS (loaded once/block from L2); A staged once per 64-row tile
// for the FULL K=256 with XOR-swizzled LDS ([row][col^((row&7)<<4)]).
// Block: 256 thr = 4 waves, wave w owns cols [w*64, w*64+64) of all 64 rows.
// Grid-stride over NT/64 tiles. One barrier pair per tile.

__global__ __launch_bounds__(256) void k_gemm(const ushort_t* __restrict__ xh,
                                              const ushort_t* __restrict__ Wt,
                                              unsigned char* __restrict__ z, int NT) {
    __shared__ __align__(16) char AsRaw[64 * 512];    // 32 KB: 64 rows x 512B (swizzled)
    __shared__ __align__(16) char Rep[4][4096];       // 16 KB: per-wave fp8 repack
    int tid = threadIdx.x;
    int wave = tid >> 6, lane = tid & 63;
    int rl = lane & 15, hi = lane >> 4;               // hi in 0..3

    // ---- W fragments into registers: wave owns n-cols [wave*64, +64) ----
    f16x8 bf[4][8];
    #pragma unroll
    for (int ni = 0; ni < 4; ni++)
        #pragma unroll
        for (int c = 0; c < 8; c++)
            bf[ni][c] = *(const f16x8*)(Wt + (size_t)(wave * 64 + ni * 16 + rl) * 256
                                        + c * 32 + hi * 8);

    int ntiles = NT / 64;
    for (int t = blockIdx.x; t < ntiles; t += gridDim.x) {
        size_t rowbase = (size_t)t * 64;

        // ---- stage A tile: 64 rows x 256 fp16, swizzled write ----
        #pragma unroll
        for (int p = 0; p < 8; p++) {
            int idx = p * 256 + tid;          // 2048 chunks of 16B
            int row = idx >> 5;
            int colb = (idx & 31) * 16;
            uint4 vsrc = *(const uint4*)(xh + (rowbase + row) * H_DIM + (idx & 31) * 8);
            *(uint4*)(AsRaw + row * 512 + (colb ^ ((row & 7) << 4))) = vsrc;
        }
        __syncthreads();

        // ---- MFMA: 8 k-chunks x (4 mi x 4 ni) ----
        f32x4 acc[4][4];
        #pragma unroll
        for (int mi = 0; mi < 4; mi++)
            #pragma unroll
            for (int ni = 0; ni < 4; ni++)
                acc[mi][ni] = (f32x4){0.f, 0.f, 0.f, 0.f};

        #pragma unroll
        for (int c = 0; c < 8; c++) {
            f16x8 af[4];
            #pragma unroll
            for (int mi = 0; mi < 4; mi++) {
                int row = mi * 16 + rl;
                int colb = c * 64 + hi * 16;
                af[mi] = *(const f16x8*)(AsRaw + row * 512 + (colb ^ ((row & 7) << 4)));
            }
            #pragma unroll
            for (int mi = 0; mi < 4; mi++)
                #pragma unroll
                for (int ni = 0; ni < 4; ni++)
                    acc[mi][ni] = __builtin_amdgcn_mfma_f32_16x16x32_f16(
                        af[mi], bf[ni][c], acc[mi][ni], 0, 0, 0);
        }
        __syncthreads();   // As free for next tile's stage

        // ---- epilogue: fp8 pack -> per-wave LDS slice -> coalesced stores ----
        char* slice = &Rep[wave][0];
        #pragma unroll
        for (int mi = 0; mi < 4; mi++)
            #pragma unroll
            for (int ni = 0; ni < 4; ni++)
                #pragma unroll
                for (int r = 0; r < 4; r++) {
                    float vv = acc[mi][ni][r];
                    int pk = __builtin_amdgcn_cvt_pk_fp8_f32(vv, vv, 0, false);
                    slice[(mi * 16 + hi * 4 + r) * 64 + ni * 16 + rl] = (char)(pk & 0xFF);
                }
        #pragma unroll
        for (int p = 0; p < 4; p++) {
            uint4 val = *(const uint4*)(slice + p * 1024 + lane * 16);
            int lrow = p * 16 + (lane >> 2);
            int lcolb = (lane & 3) * 16;
            *(uint4*)(z + (rowbase + lrow) * 256 + wave * 64 + lcolb) = val;
        }
    }
}

// ---------- aggregate + bias + leaky + residual (in-place fp16 xh update) ----------
// TWO nodes per wave (natural order); half-wave (32 lanes x 8B) per 256B fp8 row.
// Metadata loaded once, shfl broadcast. Pipelined: prefetch next 4 rows during FMA.

__global__ void k_aggres(const unsigned char* __restrict__ z, const int* __restrict__ startp,
                         const int* __restrict__ cnt, const int2* __restrict__ ecsr,
                         const float* __restrict__ dis, const float* __restrict__ bias,
                         ushort_t* __restrict__ xh, int NT) {
    int tid = threadIdx.x;
    int wave = tid >> 6, lane = tid & 63;
    int h = lane >> 5, hl = lane & 31;
    int v = blockIdx.x * 8 + wave * 2 + h;
    if (v >= NT) return;

    float d = dis[v];
    int s = startp[v], cv = cnt[v];

    int nsrc = 0;
    float nw = 0.f;
    if (hl < cv) {
        int2 ec = ecsr[s + hl];
        nsrc = ec.x;
        nw = __int_as_float(ec.y);
    }

    int cv0 = __shfl(cv, 0);
    int cv1 = __shfl(cv, 32);
    int cvmax = cv0 > cv1 ? cv0 : cv1;
    int inl = cvmax > 32 ? 32 : cvmax;
    int iters = (inl + 3) & ~3;

    uint2 a = *(const uint2*)(z + (size_t)v * 256 + hl * 8);
    us8 xr = *(const us8*)(xh + (size_t)v * H_DIM + hl * 8);
    float4 bv0 = *(const float4*)(bias + hl * 8);
    float4 bv1 = *(const float4*)(bias + hl * 8 + 4);

    float sn = d * d;
    float acc[8];
    {
        f32x2 p0 = __builtin_amdgcn_cvt_pk_f32_fp8(a.x, false);
        f32x2 p1 = __builtin_amdgcn_cvt_pk_f32_fp8(a.x, true);
        f32x2 p2 = __builtin_amdgcn_cvt_pk_f32_fp8(a.y, false);
        f32x2 p3 = __builtin_amdgcn_cvt_pk_f32_fp8(a.y, true);
        acc[0] = sn * p0[0]; acc[1] = sn * p0[1];
        acc[2] = sn * p1[0]; acc[3] = sn * p1[1];
        acc[4] = sn * p2[0]; acc[5] = sn * p2[1];
        acc[6] = sn * p3[0]; acc[7] = sn * p3[1];
    }

    int base = h << 5;
    uint2 b[4];
    float w[4];
    #pragma unroll
    for (int j = 0; j < 4; j++) {
        int ii = __shfl(nsrc, base + j);
        w[j]   = __shfl(nw,   base + j);
        b[j] = *(const uint2*)(z + (size_t)ii * 256 + hl * 8);
    }
    for (int k = 0; k < iters; k += 4) {
        uint2 nb[4];
        float nwt[4];
        bool more = (k + 4) < iters;
        if (more) {
            #pragma unroll
            for (int j = 0; j < 4; j++) {
                int ii = __shfl(nsrc, base + k + 4 + j);
                nwt[j] = __shfl(nw,   base + k + 4 + j);
                nb[j] = *(const uint2*)(z + (size_t)ii * 256 + hl * 8);
            }
        }
        #pragma unroll
        for (int j = 0; j < 4; j++) {
            f32x2 p0 = __builtin_amdgcn_cvt_pk_f32_fp8(b[j].x, false);
            f32x2 p1 = __builtin_amdgcn_cvt_pk_f32_fp8(b[j].x, true);
            f32x2 p2 = __builtin_amdgcn_cvt_pk_f32_fp8(b[j].y, false);
            f32x2 p3 = __builtin_amdgcn_cvt_pk_f32_fp8(b[j].y, true);
            float ww = w[j];
            acc[0] += ww * p0[0]; acc[1] += ww * p0[1];
            acc[2] += ww * p1[0]; acc[3] += ww * p1[1];
            acc[4] += ww * p2[0]; acc[5] += ww * p2[1];
            acc[6] += ww * p3[0]; acc[7] += ww * p3[1];
        }
        if (more) {
            #pragma unroll
            for (int j = 0; j < 4; j++) { b[j] = nb[j]; w[j] = nwt[j]; }
        }
    }
    for (int k = 32; k < cv; k++) {
        int2 ec = ecsr[s + k];
        float ww = __int_as_float(ec.y);
        uint2 bb = *(const uint2*)(z + (size_t)ec.x * 256 + hl * 8);
        f32x2 p0 = __builtin_amdgcn_cvt_pk_f32_fp8(bb.x, false);
        f32x2 p1 = __builtin_amdgcn_cvt_pk_f32_fp8(bb.x, true);
        f32x2 p2 = __builtin_amdgcn_cvt_pk_f32_fp8(bb.y, false);
        f32x2 p3 = __builtin_amdgcn_cvt_pk_f32_fp8(bb.y, true);
        acc[0] += ww * p0[0]; acc[1] += ww * p0[1];
        acc[2] += ww * p1[0]; acc[3] += ww * p1[1];
        acc[4] += ww * p2[0]; acc[5] += ww * p2[1];
        acc[6] += ww * p3[0]; acc[7] += ww * p3[1];
    }

    us8 o;
    o[0] = f2h(h2f(xr[0]) + lrelu(acc[0] + bv0.x));
    o[1] = f2h(h2f(xr[1]) + lrelu(acc[1] + bv0.y));
    o[2] = f2h(h2f(xr[2]) + lrelu(acc[2] + bv0.z));
    o[3] = f2h(h2f(xr[3]) + lrelu(acc[3] + bv0.w));
    o[4] = f2h(h2f(xr[4]) + lrelu(acc[4] + bv1.x));
    o[5] = f2h(h2f(xr[5]) + lrelu(acc[5] + bv1.y));
    o[6] = f2h(h2f(xr[6]) + lrelu(acc[6] + bv1.z));
    o[7] = f2h(h2f(xr[7]) + lrelu(acc[7] + bv1.w));
    *(us8*)(xh + (size_t)v * H_DIM + hl * 8) = o;
}

// ---------- FINAL layer: aggregate + residual, fused block-level pooling ----------
// Same gather body as k_aggres, but xh is NOT written (nothing consumes it after);
// instead the block's 8 node-rows are LDS-reduced into one f32 partial row.

__global__ void k_aggres_pool(const unsigned char* __restrict__ z, const int* __restrict__ startp,
                              const int* __restrict__ cnt, const int2* __restrict__ ecsr,
                              const float* __restrict__ dis, const float* __restrict__ bias,
                              const ushort_t* __restrict__ xh, float* __restrict__ partial,
                              int NT) {
    __shared__ float red[8][256];
    int tid = threadIdx.x;
    int wave = tid >> 6, lane = tid & 63;
    int h = lane >> 5, hl = lane & 31;
    int node = wave * 2 + h;               // 0..7 within block
    int v = blockIdx.x * 8 + node;

    float o[8];
    #pragma unroll
    for (int c = 0; c < 8; c++) o[c] = 0.f;

    if (v < NT) {
        float d = dis[v];
        int s = startp[v], cv = cnt[v];

        int nsrc = 0;
        float nw = 0.f;
        if (hl < cv) {
            int2 ec = ecsr[s + hl];
            nsrc = ec.x;
            nw = __int_as_float(ec.y);
        }

        int cv0 = __shfl(cv, 0);
        int cv1 = __shfl(cv, 32);
        int cvmax = cv0 > cv1 ? cv0 : cv1;
        int inl = cvmax > 32 ? 32 : cvmax;
        int iters = (inl + 3) & ~3;

        uint2 a = *(const uint2*)(z + (size_t)v * 256 + hl * 8);
        us8 xr = *(const us8*)(xh + (size_t)v * H_DIM + hl * 8);
        float4 bv0 = *(const float4*)(bias + hl * 8);
        float4 bv1 = *(const float4*)(bias + hl * 8 + 4);

        float sn = d * d;
        float acc[8];
        {
            f32x2 p0 = __builtin_amdgcn_cvt_pk_f32_fp8(a.x, false);
            f32x2 p1 = __builtin_amdgcn_cvt_pk_f32_fp8(a.x, true);
            f32x2 p2 = __builtin_amdgcn_cvt_pk_f32_fp8(a.y, false);
            f32x2 p3 = __builtin_amdgcn_cvt_pk_f32_fp8(a.y, true);
            acc[0] = sn * p0[0]; acc[1] = sn * p0[1];
            acc[2] = sn * p1[0]; acc[3] = sn * p1[1];
            acc[4] = sn * p2[0]; acc[5] = sn * p2[1];
            acc[6] = sn * p3[0]; acc[7] = sn * p3[1];
        }

        int base = h << 5;
        uint2 b[4];
        float w[4];
        #pragma unroll
        for (int j = 0; j < 4; j++) {
            int ii = __shfl(nsrc, base + j);
            w[j]   = __shfl(nw,   base + j);
            b[j] = *(const uint2*)(z + (size_t)ii * 256 + hl * 8);
        }
        for (int k = 0; k < iters; k += 4) {
            uint2 nb[4];
            float nwt[4];
            bool more = (k + 4) < iters;
            if (more) {
                #pragma unroll
                for (int j = 0; j < 4; j++) {
                    int ii = __shfl(nsrc, base + k + 4 + j);
                    nwt[j] = __shfl(nw,   base + k + 4 + j);
                    nb[j] = *(const uint2*)(z + (size_t)ii * 256 + hl * 8);
                }
            }
            #pragma unroll
            for (int j = 0; j < 4; j++) {
                f32x2 p0 = __builtin_amdgcn_cvt_pk_f32_fp8(b[j].x, false);
                f32x2 p1 = __builtin_amdgcn_cvt_pk_f32_fp8(b[j].x, true);
                f32x2 p2 = __builtin_amdgcn_cvt_pk_f32_fp8(b[j].y, false);
                f32x2 p3 = __builtin_amdgcn_cvt_pk_f32_fp8(b[j].y, true);
                float ww = w[j];
                acc[0] += ww * p0[0]; acc[1] += ww * p0[1];
                acc[2] += ww * p1[0]; acc[3] += ww * p1[1];
                acc[4] += ww * p2[0]; acc[5] += ww * p2[1];
                acc[6] += ww * p3[0]; acc[7] += ww * p3[1];
            }
            if (more) {
                #pragma unroll
                for (int j = 0; j < 4; j++) { b[j] = nb[j]; w[j] = nwt[j]; }
            }
        }
        for (int k = 32; k < cv; k++) {
            int2 ec = ecsr[s + k];
            float ww = __int_as_float(ec.y);
            uint2 bb = *(const uint2*)(z + (size_t)ec.x * 256 + hl * 8);
            f32x2 p0 = __builtin_amdgcn_cvt_pk_f32_fp8(bb.x, false);
            f32x2 p1 = __builtin_amdgcn_cvt_pk_f32_fp8(bb.x, true);
            f32x2 p2 = __builtin_amdgcn_cvt_pk_f32_fp8(bb.y, false);
            f32x2 p3 = __builtin_amdgcn_cvt_pk_f32_fp8(bb.y, true);
            acc[0] += ww * p0[0]; acc[1] += ww * p0[1];
            acc[2] += ww * p1[0]; acc[3] += ww * p1[1];
            acc[4] += ww * p2[0]; acc[5] += ww * p2[1];
            acc[6] += ww * p3[0]; acc[7] += ww * p3[1];
        }

        o[0] = h2f(xr[0]) + lrelu(acc[0] + bv0.x);
        o[1] = h2f(xr[1]) + lrelu(acc[1] + bv0.y);
        o[2] = h2f(xr[2]) + lrelu(acc[2] + bv0.z);
        o[3] = h2f(xr[3]) + lrelu(acc[3] + bv0.w);
        o[4] = h2f(xr[4]) + lrelu(acc[4] + bv1.x);
        o[5] = h2f(xr[5]) + lrelu(acc[5] + bv1.y);
        o[6] = h2f(xr[6]) + lrelu(acc[6] + bv1.z);
        o[7] = h2f(xr[7]) + lrelu(acc[7] + bv1.w);
    }

    // stash this node's 8 channels, then block-reduce 8 nodes -> 1 partial row
    #pragma unroll
    for (int c = 0; c < 8; c++) red[node][hl * 8 + c] = o[c];
    __syncthreads();
    int t = tid;
    float sum = 0.f;
    #pragma unroll
    for (int n = 0; n < 8; n++) sum += red[n][t];
    partial[(size_t)blockIdx.x * 256 + t] = sum;
}

// ---------- pooling tail (partials: one f32 row per 8-node block) + head ----------

__global__ void k_pool2(const float* __restrict__ partial, float* __restrict__ partial2,
                        int rowsPerChunk) {
    int blk = blockIdx.x, t = threadIdx.x;
    size_t rowbase = (size_t)blk * rowsPerChunk;
    float s = 0.f;
    for (int j = 0; j < rowsPerChunk; j++)
        s += partial[(rowbase + j) * 256 + t];
    partial2[(size_t)blk * 256 + t] = s;
}

__global__ void k_pool3(const float* __restrict__ partial2, float* __restrict__ pooled,
                        int chunksPerBatch, float inv) {
    int b = blockIdx.x, t = threadIdx.x;
    float s = 0.f;
    for (int j = 0; j < chunksPerBatch; j++)
        s += partial2[((size_t)b * chunksPerBatch + j) * 256 + t];
    pooled[b * 256 + t] = s * inv;
}

__global__ void k_head(const float* __restrict__ pooled, const float* __restrict__ Wh,
                       const float* __restrict__ bh, float* __restrict__ out) {
    int b = blockIdx.x, o = threadIdx.x;
    float acc = bh[o];
    for (int h = 0; h < H_DIM; h++) acc += pooled[b * H_DIM + h] * Wh[h * OUT_DIM + o];
    out[b * OUT_DIM + o] = acc;
}

// ---------- host ----------

extern "C" void kernel_launch(void* const* d_in, const int* in_sizes, int n_in,
                              void* d_out, int out_size, void* d_ws, size_t ws_size,
                              hipStream_t stream) {
    const float* sst  = (const float*)d_in[0];
    const int*   mask = (const int*)d_in[1];
    const int*   eidx = (const int*)d_in[2];
    const float* W1   = (const float*)d_in[3];
    const float* b1   = (const float*)d_in[4];
    const float* Ws   = (const float*)d_in[5];
    const float* bs   = (const float*)d_in[6];
    const float* Wh   = (const float*)d_in[7];
    const float* bh   = (const float*)d_in[8];

    const int B  = out_size / OUT_DIM;               // 2
    const int Nn = in_sizes[1];                      // 65536
    const int E  = in_sizes[2] / 2;                  // 1048576
    const int F  = in_sizes[0] / B;                  // 686364
    const int DEPTH = in_sizes[5] / (H_DIM * H_DIM); // 8
    const int NT = B * Nn;                           // 131072

    // workspace carve-up (256B aligned) — total ~139 MB
    size_t off = 0;
    char* base = (char*)d_ws;
    auto alloc = [&](size_t bytes) -> void* {
        void* p = base + off;
        off += (bytes + 255) & ~(size_t)255;
        return p;
    };
    ushort_t*      xh      = (ushort_t*)alloc((size_t)NT * H_DIM * 2);  // 67.1 MB fp16 residual
    unsigned char* zbuf    = (unsigned char*)alloc((size_t)NT * 256);   // 33.5 MB fp8
    float*    x0      = (float*)alloc((size_t)NT * 4);
    float*    y0      = (float*)alloc((size_t)NT * 4);
    int*      cnt     = (int*)alloc((size_t)NT * 4);
    int*      startp  = (int*)alloc((size_t)NT * 4);
    float*    dis     = (float*)alloc((size_t)NT * 4);
    int*      bsum    = (int*)alloc(4096);
    int*      bpre    = (int*)alloc(4096);
    int*      rank    = (int*)alloc((size_t)E * 4);                     // 4 MB
    int2*     ecsr    = (int2*)alloc((size_t)E * 8);                    // 8 MB
    ushort_t* Wt      = (ushort_t*)alloc((size_t)DEPTH * H_DIM * H_DIM * 2);  // 1 MB fp16
    float*    partial = (float*)alloc((size_t)(NT / 8) * 256 * 4);      // 16.8 MB
    float*    partial2= (float*)alloc((size_t)64 * 256 * 4);
    float*    pooled  = (float*)alloc((size_t)B * 256 * 4);
    if (off > ws_size) return;   // workspace too small: fail visibly

    const int* esrc = eidx;
    const int* edst = eidx + E;

    dim3 blk(256);
    int gNT = (NT + 255) / 256;
    int gE  = (E + 255) / 256;
    int nb  = gNT;               // 512 scan blocks

    hipMemsetAsync(cnt, 0, (size_t)NT * 4, stream);

    k_gather_x0<<<gNT, blk, 0, stream>>>(sst, mask, x0, NT, Nn, F);
    k_count<<<gE, blk, 0, stream>>>(edst, cnt, rank, E);
    k_dis<<<gNT, blk, 0, stream>>>(cnt, dis, NT);
    k_scan_block<<<nb, blk, 0, stream>>>(cnt, bsum, NT);
    k_scan_top<<<1, 512, 0, stream>>>(bsum, bpre, nb);
    k_scan_scatter<<<nb, blk, 0, stream>>>(cnt, bpre, startp, NT);
    k_fill<<<gE, blk, 0, stream>>>(esrc, edst, rank, startp, dis, ecsr, E);
    k_prepW<<<(DEPTH * H_DIM * H_DIM + 255) / 256, blk, 0, stream>>>(Ws, Wt, DEPTH * H_DIM * H_DIM);

    // layer 1: scalar -> H (fp16 residual stream)
    k_agg0<<<gNT, blk, 0, stream>>>(x0, startp, cnt, ecsr, dis, y0, NT);
    k_expand<<<(NT * 64 + 255) / 256, blk, 0, stream>>>(x0, y0, W1, b1, xh, NT);

    // layers 2..8: z = xh@W (fp8 out), then aggregate+bias+leaky+residual into xh
    for (int l = 0; l < DEPTH - 1; l++) {
        k_gemm<<<512, blk, 0, stream>>>(xh, Wt + (size_t)l * H_DIM * H_DIM, zbuf, NT);
        k_aggres<<<NT / 8, blk, 0, stream>>>(zbuf, startp, cnt, ecsr, dis,
                                             bs + (size_t)l * H_DIM, xh, NT);
    }
    // layer 9: fused aggregate + residual + block pooling (no xh write)
    {
        int l = DEPTH - 1;
        k_gemm<<<512, blk, 0, stream>>>(xh, Wt + (size_t)l * H_DIM * H_DIM, zbuf, NT);
        k_aggres_pool<<<NT / 8, blk, 0, stream>>>(zbuf, startp, cnt, ecsr, dis,
                                                  bs + (size_t)l * H_DIM, xh, partial, NT);
    }

    // pool tail: 16384 partial rows -> 32 -> 2
    int pblocks = NT / 8;                  // 16384
    int chunksPerBatch = 16;
    int rowsPerChunk = (pblocks / B) / chunksPerBatch;   // 512
    k_pool2<<<B * chunksPerBatch, blk, 0, stream>>>(partial, partial2, rowsPerChunk);
    k_pool3<<<B, blk, 0, stream>>>(partial2, pooled, chunksPerBatch, 1.0f / (float)Nn);
    k_head<<<B, blk, 0, stream>>>(pooled, Wh, bh, (float*)d_out);
}

// Round 17
// 833.889 us; speedup vs baseline: 1.1236x; 1.1236x over previous
//
#include <hip/hip_runtime.h>

typedef unsigned short ushort_t;
typedef _Float16 f16x8 __attribute__((ext_vector_type(8)));
typedef float f32x4 __attribute__((ext_vector_type(4)));
typedef float f32x2 __attribute__((ext_vector_type(2)));
typedef unsigned short us8 __attribute__((ext_vector_type(8)));

#define H_DIM 256
#define OUT_DIM 256

__device__ inline float lrelu(float v) { return v > 0.f ? v : 0.01f * v; }

__device__ inline unsigned short f2h(float f) {
    _Float16 h = (_Float16)f;
    unsigned short u;
    __builtin_memcpy(&u, &h, 2);
    return u;
}

__device__ inline float h2f(unsigned short u) {
    _Float16 h;
    __builtin_memcpy(&h, &u, 2);
    return (float)h;
}

// ---------- prep kernels ----------

__global__ void k_gather_x0(const float* __restrict__ sst, const int* __restrict__ mask,
                            float* __restrict__ x0, int NT, int Nn, int F) {
    int v = blockIdx.x * 256 + threadIdx.x;
    if (v < NT) {
        int b = v / Nn;
        int i = v - b * Nn;
        x0[v] = sst[(size_t)b * F + mask[i]];
    }
}

// count + record each edge's rank within its dst bucket (coalesced store)
__global__ void k_count(const int* __restrict__ dst, int* __restrict__ cnt,
                        int* __restrict__ rank, int E) {
    int e = blockIdx.x * 256 + threadIdx.x;
    if (e < E) rank[e] = atomicAdd(&cnt[dst[e]], 1);
}

__global__ void k_dis(const int* __restrict__ cnt, float* __restrict__ dis, int NT) {
    int v = blockIdx.x * 256 + threadIdx.x;
    if (v < NT) dis[v] = rsqrtf((float)cnt[v] + 1.0f);
}

__global__ void k_scan_block(const int* __restrict__ cnt, int* __restrict__ bsum, int NT) {
    __shared__ int s[256];
    int i = blockIdx.x * 256 + threadIdx.x;
    s[threadIdx.x] = (i < NT) ? cnt[i] : 0;
    __syncthreads();
    for (int o = 128; o > 0; o >>= 1) {
        if (threadIdx.x < o) s[threadIdx.x] += s[threadIdx.x + o];
        __syncthreads();
    }
    if (threadIdx.x == 0) bsum[blockIdx.x] = s[0];
}

__global__ void k_scan_top(const int* __restrict__ bsum, int* __restrict__ bpre, int nb) {
    __shared__ int s[512];
    int t = threadIdx.x;
    int v = (t < nb) ? bsum[t] : 0;
    s[t] = v;
    __syncthreads();
    for (int o = 1; o < nb; o <<= 1) {
        int add = (t >= o) ? s[t - o] : 0;
        __syncthreads();
        s[t] += add;
        __syncthreads();
    }
    if (t < nb) bpre[t] = s[t] - v;   // exclusive
}

__global__ void k_scan_scatter(const int* __restrict__ cnt, const int* __restrict__ bpre,
                               int* __restrict__ startp, int NT) {
    __shared__ int s[256];
    int t = threadIdx.x;
    int i = blockIdx.x * 256 + t;
    int v = (i < NT) ? cnt[i] : 0;
    s[t] = v;
    __syncthreads();
    for (int o = 1; o < 256; o <<= 1) {
        int add = (t >= o) ? s[t - o] : 0;
        __syncthreads();
        s[t] += add;
        __syncthreads();
    }
    int excl = s[t] - v + bpre[blockIdx.x];
    if (i < NT) startp[i] = excl;
}

// fill: atomic-free; one packed 8B store per edge {src, cnorm bits}
__global__ void k_fill(const int* __restrict__ src, const int* __restrict__ dst,
                       const int* __restrict__ rank, const int* __restrict__ startp,
                       const float* __restrict__ dis, int2* __restrict__ ecsr, int E) {
    int e = blockIdx.x * 256 + threadIdx.x;
    if (e < E) {
        int s = src[e], d = dst[e];
        float nw = dis[s] * dis[d];
        int p = startp[d] + rank[e];
        ecsr[p] = make_int2(s, __float_as_int(nw));
    }
}

__global__ void k_prepW(const float* __restrict__ Ws, ushort_t* __restrict__ Wt, int total) {
    int idx = blockIdx.x * 256 + threadIdx.x;
    if (idx < total) {
        int l = idx >> 16;          // layer
        int rem = idx & 65535;
        int k = rem >> 8;           // input dim
        int n = rem & 255;          // output dim
        Wt[(l << 16) + (n << 8) + k] = f2h(Ws[idx]);
    }
}

// ---------- layer 1 (scalar input) ----------

__global__ void k_agg0(const float* __restrict__ x0, const int* __restrict__ startp,
                       const int* __restrict__ cnt, const int2* __restrict__ ecsr,
                       const float* __restrict__ dis, float* __restrict__ y0, int NT) {
    int v = blockIdx.x * 256 + threadIdx.x;
    if (v >= NT) return;
    float d = dis[v];
    float acc = d * d * x0[v];
    int s = startp[v], e = s + cnt[v];
    for (int i = s; i < e; i++) {
        int2 ec = ecsr[i];
        acc += __int_as_float(ec.y) * x0[ec.x];
    }
    y0[v] = acc;
}

__global__ void k_expand(const float* __restrict__ x0, const float* __restrict__ y0,
                         const float* __restrict__ W1, const float* __restrict__ b1,
                         ushort_t* __restrict__ xh, int NT) {
    int idx = blockIdx.x * 256 + threadIdx.x;      // one float4-worth each, NT*64 total
    int v = idx >> 6;
    int q = idx & 63;
    if (v >= NT) return;
    float xv = x0[v], yv = y0[v];
    float4 w = ((const float4*)W1)[q];
    float4 b = ((const float4*)b1)[q];
    ushort4 o;
    o.x = f2h(xv + lrelu(yv * w.x + b.x));
    o.y = f2h(xv + lrelu(yv * w.y + b.y));
    o.z = f2h(xv + lrelu(yv * w.z + b.z));
    o.w = f2h(xv + lrelu(yv * w.w + b.w));
    ((ushort4*)xh)[(size_t)v * 64 + q] = o;
}

// ---------- GEMM: z = xh @ W (fp16 MFMA, f32 acc, fp8 e4m3 out) ----------
// W held in REGISTERS (loaded once/block from L2); A staged once per 64-row tile
// for the FULL K=256 with XOR-swizzled LDS ([row][col^((row&7)<<4)]).
// Block: 256 thr = 4 waves, wave w owns cols [w*64, w*64+64) of all 64 rows.
// Grid-stride over NT/64 tiles. One barrier pair per tile.

__global__ __launch_bounds__(256) void k_gemm(const ushort_t* __restrict__ xh,
                                              const ushort_t* __restrict__ Wt,
                                              unsigned char* __restrict__ z, int NT) {
    __shared__ __align__(16) char AsRaw[64 * 512];    // 32 KB: 64 rows x 512B (swizzled)
    __shared__ __align__(16) char Rep[4][4096];       // 16 KB: per-wave fp8 repack
    int tid = threadIdx.x;
    int wave = tid >> 6, lane = tid & 63;
    int rl = lane & 15, hi = lane >> 4;               // hi in 0..3

    // ---- W fragments into registers: wave owns n-cols [wave*64, +64) ----
    f16x8 bf[4][8];
    #pragma unroll
    for (int ni = 0; ni < 4; ni++)
        #pragma unroll
        for (int c = 0; c < 8; c++)
            bf[ni][c] = *(const f16x8*)(Wt + (size_t)(wave * 64 + ni * 16 + rl) * 256
                                        + c * 32 + hi * 8);

    int ntiles = NT / 64;
    for (int t = blockIdx.x; t < ntiles; t += gridDim.x) {
        size_t rowbase = (size_t)t * 64;

        // ---- stage A tile: 64 rows x 256 fp16, swizzled write ----
        #pragma unroll
        for (int p = 0; p < 8; p++) {
            int idx = p * 256 + tid;          // 2048 chunks of 16B
            int row = idx >> 5;
            int colb = (idx & 31) * 16;
            uint4 vsrc = *(const uint4*)(xh + (rowbase + row) * H_DIM + (idx & 31) * 8);
            *(uint4*)(AsRaw + row * 512 + (colb ^ ((row & 7) << 4))) = vsrc;
        }
        __syncthreads();

        // ---- MFMA: 8 k-chunks x (4 mi x 4 ni) ----
        f32x4 acc[4][4];
        #pragma unroll
        for (int mi = 0; mi < 4; mi++)
            #pragma unroll
            for (int ni = 0; ni < 4; ni++)
                acc[mi][ni] = (f32x4){0.f, 0.f, 0.f, 0.f};

        #pragma unroll
        for (int c = 0; c < 8; c++) {
            f16x8 af[4];
            #pragma unroll
            for (int mi = 0; mi < 4; mi++) {
                int row = mi * 16 + rl;
                int colb = c * 64 + hi * 16;
                af[mi] = *(const f16x8*)(AsRaw + row * 512 + (colb ^ ((row & 7) << 4)));
            }
            #pragma unroll
            for (int mi = 0; mi < 4; mi++)
                #pragma unroll
                for (int ni = 0; ni < 4; ni++)
                    acc[mi][ni] = __builtin_amdgcn_mfma_f32_16x16x32_f16(
                        af[mi], bf[ni][c], acc[mi][ni], 0, 0, 0);
        }
        __syncthreads();   // As free for next tile's stage

        // ---- epilogue: fp8 pack -> per-wave LDS slice -> coalesced stores ----
        char* slice = &Rep[wave][0];
        #pragma unroll
        for (int mi = 0; mi < 4; mi++)
            #pragma unroll
            for (int ni = 0; ni < 4; ni++)
                #pragma unroll
                for (int r = 0; r < 4; r++) {
                    float vv = acc[mi][ni][r];
                    int pk = __builtin_amdgcn_cvt_pk_fp8_f32(vv, vv, 0, false);
                    slice[(mi * 16 + hi * 4 + r) * 64 + ni * 16 + rl] = (char)(pk & 0xFF);
                }
        #pragma unroll
        for (int p = 0; p < 4; p++) {
            uint4 val = *(const uint4*)(slice + p * 1024 + lane * 16);
            int lrow = p * 16 + (lane >> 2);
            int lcolb = (lane & 3) * 16;
            *(uint4*)(z + (rowbase + lrow) * 256 + wave * 64 + lcolb) = val;
        }
    }
}

// ---------- aggregate + bias + leaky + residual (in-place fp16 xh update) ----------
// TWO nodes per wave (natural order); half-wave (32 lanes x 8B) per 256B fp8 row.
// Metadata loaded once, shfl broadcast. Pipelined: prefetch next 4 rows during FMA.

__global__ void k_aggres(const unsigned char* __restrict__ z, const int* __restrict__ startp,
                         const int* __restrict__ cnt, const int2* __restrict__ ecsr,
                         const float* __restrict__ dis, const float* __restrict__ bias,
                         ushort_t* __restrict__ xh, int NT) {
    int tid = threadIdx.x;
    int wave = tid >> 6, lane = tid & 63;
    int h = lane >> 5, hl = lane & 31;
    int v = blockIdx.x * 8 + wave * 2 + h;
    if (v >= NT) return;

    float d = dis[v];
    int s = startp[v], cv = cnt[v];

    int nsrc = 0;
    float nw = 0.f;
    if (hl < cv) {
        int2 ec = ecsr[s + hl];
        nsrc = ec.x;
        nw = __int_as_float(ec.y);
    }

    int cv0 = __shfl(cv, 0);
    int cv1 = __shfl(cv, 32);
    int cvmax = cv0 > cv1 ? cv0 : cv1;
    int inl = cvmax > 32 ? 32 : cvmax;
    int iters = (inl + 3) & ~3;

    uint2 a = *(const uint2*)(z + (size_t)v * 256 + hl * 8);
    us8 xr = *(const us8*)(xh + (size_t)v * H_DIM + hl * 8);
    float4 bv0 = *(const float4*)(bias + hl * 8);
    float4 bv1 = *(const float4*)(bias + hl * 8 + 4);

    float sn = d * d;
    float acc[8];
    {
        f32x2 p0 = __builtin_amdgcn_cvt_pk_f32_fp8(a.x, false);
        f32x2 p1 = __builtin_amdgcn_cvt_pk_f32_fp8(a.x, true);
        f32x2 p2 = __builtin_amdgcn_cvt_pk_f32_fp8(a.y, false);
        f32x2 p3 = __builtin_amdgcn_cvt_pk_f32_fp8(a.y, true);
        acc[0] = sn * p0[0]; acc[1] = sn * p0[1];
        acc[2] = sn * p1[0]; acc[3] = sn * p1[1];
        acc[4] = sn * p2[0]; acc[5] = sn * p2[1];
        acc[6] = sn * p3[0]; acc[7] = sn * p3[1];
    }

    int base = h << 5;
    uint2 b[4];
    float w[4];
    #pragma unroll
    for (int j = 0; j < 4; j++) {
        int ii = __shfl(nsrc, base + j);
        w[j]   = __shfl(nw,   base + j);
        b[j] = *(const uint2*)(z + (size_t)ii * 256 + hl * 8);
    }
    for (int k = 0; k < iters; k += 4) {
        uint2 nb[4];
        float nwt[4];
        bool more = (k + 4) < iters;
        if (more) {
            #pragma unroll
            for (int j = 0; j < 4; j++) {
                int ii = __shfl(nsrc, base + k + 4 + j);
                nwt[j] = __shfl(nw,   base + k + 4 + j);
                nb[j] = *(const uint2*)(z + (size_t)ii * 256 + hl * 8);
            }
        }
        #pragma unroll
        for (int j = 0; j < 4; j++) {
            f32x2 p0 = __builtin_amdgcn_cvt_pk_f32_fp8(b[j].x, false);
            f32x2 p1 = __builtin_amdgcn_cvt_pk_f32_fp8(b[j].x, true);
            f32x2 p2 = __builtin_amdgcn_cvt_pk_f32_fp8(b[j].y, false);
            f32x2 p3 = __builtin_amdgcn_cvt_pk_f32_fp8(b[j].y, true);
            float ww = w[j];
            acc[0] += ww * p0[0]; acc[1] += ww * p0[1];
            acc[2] += ww * p1[0]; acc[3] += ww * p1[1];
            acc[4] += ww * p2[0]; acc[5] += ww * p2[1];
            acc[6] += ww * p3[0]; acc[7] += ww * p3[1];
        }
        if (more) {
            #pragma unroll
            for (int j = 0; j < 4; j++) { b[j] = nb[j]; w[j] = nwt[j]; }
        }
    }
    for (int k = 32; k < cv; k++) {
        int2 ec = ecsr[s + k];
        float ww = __int_as_float(ec.y);
        uint2 bb = *(const uint2*)(z + (size_t)ec.x * 256 + hl * 8);
        f32x2 p0 = __builtin_amdgcn_cvt_pk_f32_fp8(bb.x, false);
        f32x2 p1 = __builtin_amdgcn_cvt_pk_f32_fp8(bb.x, true);
        f32x2 p2 = __builtin_amdgcn_cvt_pk_f32_fp8(bb.y, false);
        f32x2 p3 = __builtin_amdgcn_cvt_pk_f32_fp8(bb.y, true);
        acc[0] += ww * p0[0]; acc[1] += ww * p0[1];
        acc[2] += ww * p1[0]; acc[3] += ww * p1[1];
        acc[4] += ww * p2[0]; acc[5] += ww * p2[1];
        acc[6] += ww * p3[0]; acc[7] += ww * p3[1];
    }

    us8 o;
    o[0] = f2h(h2f(xr[0]) + lrelu(acc[0] + bv0.x));
    o[1] = f2h(h2f(xr[1]) + lrelu(acc[1] + bv0.y));
    o[2] = f2h(h2f(xr[2]) + lrelu(acc[2] + bv0.z));
    o[3] = f2h(h2f(xr[3]) + lrelu(acc[3] + bv0.w));
    o[4] = f2h(h2f(xr[4]) + lrelu(acc[4] + bv1.x));
    o[5] = f2h(h2f(xr[5]) + lrelu(acc[5] + bv1.y));
    o[6] = f2h(h2f(xr[6]) + lrelu(acc[6] + bv1.z));
    o[7] = f2h(h2f(xr[7]) + lrelu(acc[7] + bv1.w));
    *(us8*)(xh + (size_t)v * H_DIM + hl * 8) = o;
}

// ---------- FINAL layer: aggregate + residual, fused block-level pooling ----------
// Same gather body as k_aggres, but xh is NOT written (nothing consumes it after);
// instead the block's 8 node-rows are LDS-reduced into one f32 partial row.

__global__ void k_aggres_pool(const unsigned char* __restrict__ z, const int* __restrict__ startp,
                              const int* __restrict__ cnt, const int2* __restrict__ ecsr,
                              const float* __restrict__ dis, const float* __restrict__ bias,
                              const ushort_t* __restrict__ xh, float* __restrict__ partial,
                              int NT) {
    __shared__ float red[8][256];
    int tid = threadIdx.x;
    int wave = tid >> 6, lane = tid & 63;
    int h = lane >> 5, hl = lane & 31;
    int node = wave * 2 + h;               // 0..7 within block
    int v = blockIdx.x * 8 + node;

    float o[8];
    #pragma unroll
    for (int c = 0; c < 8; c++) o[c] = 0.f;

    if (v < NT) {
        float d = dis[v];
        int s = startp[v], cv = cnt[v];

        int nsrc = 0;
        float nw = 0.f;
        if (hl < cv) {
            int2 ec = ecsr[s + hl];
            nsrc = ec.x;
            nw = __int_as_float(ec.y);
        }

        int cv0 = __shfl(cv, 0);
        int cv1 = __shfl(cv, 32);
        int cvmax = cv0 > cv1 ? cv0 : cv1;
        int inl = cvmax > 32 ? 32 : cvmax;
        int iters = (inl + 3) & ~3;

        uint2 a = *(const uint2*)(z + (size_t)v * 256 + hl * 8);
        us8 xr = *(const us8*)(xh + (size_t)v * H_DIM + hl * 8);
        float4 bv0 = *(const float4*)(bias + hl * 8);
        float4 bv1 = *(const float4*)(bias + hl * 8 + 4);

        float sn = d * d;
        float acc[8];
        {
            f32x2 p0 = __builtin_amdgcn_cvt_pk_f32_fp8(a.x, false);
            f32x2 p1 = __builtin_amdgcn_cvt_pk_f32_fp8(a.x, true);
            f32x2 p2 = __builtin_amdgcn_cvt_pk_f32_fp8(a.y, false);
            f32x2 p3 = __builtin_amdgcn_cvt_pk_f32_fp8(a.y, true);
            acc[0] = sn * p0[0]; acc[1] = sn * p0[1];
            acc[2] = sn * p1[0]; acc[3] = sn * p1[1];
            acc[4] = sn * p2[0]; acc[5] = sn * p2[1];
            acc[6] = sn * p3[0]; acc[7] = sn * p3[1];
        }

        int base = h << 5;
        uint2 b[4];
        float w[4];
        #pragma unroll
        for (int j = 0; j < 4; j++) {
            int ii = __shfl(nsrc, base + j);
            w[j]   = __shfl(nw,   base + j);
            b[j] = *(const uint2*)(z + (size_t)ii * 256 + hl * 8);
        }
        for (int k = 0; k < iters; k += 4) {
            uint2 nb[4];
            float nwt[4];
            bool more = (k + 4) < iters;
            if (more) {
                #pragma unroll
                for (int j = 0; j < 4; j++) {
                    int ii = __shfl(nsrc, base + k + 4 + j);
                    nwt[j] = __shfl(nw,   base + k + 4 + j);
                    nb[j] = *(const uint2*)(z + (size_t)ii * 256 + hl * 8);
                }
            }
            #pragma unroll
            for (int j = 0; j < 4; j++) {
                f32x2 p0 = __builtin_amdgcn_cvt_pk_f32_fp8(b[j].x, false);
                f32x2 p1 = __builtin_amdgcn_cvt_pk_f32_fp8(b[j].x, true);
                f32x2 p2 = __builtin_amdgcn_cvt_pk_f32_fp8(b[j].y, false);
                f32x2 p3 = __builtin_amdgcn_cvt_pk_f32_fp8(b[j].y, true);
                float ww = w[j];
                acc[0] += ww * p0[0]; acc[1] += ww * p0[1];
                acc[2] += ww * p1[0]; acc[3] += ww * p1[1];
                acc[4] += ww * p2[0]; acc[5] += ww * p2[1];
                acc[6] += ww * p3[0]; acc[7] += ww * p3[1];
            }
            if (more) {
                #pragma unroll
                for (int j = 0; j < 4; j++) { b[j] = nb[j]; w[j] = nwt[j]; }
            }
        }
        for (int k = 32; k < cv; k++) {
            int2 ec = ecsr[s + k];
            float ww = __int_as_float(ec.y);
            uint2 bb = *(const uint2*)(z + (size_t)ec.x * 256 + hl * 8);
            f32x2 p0 = __builtin_amdgcn_cvt_pk_f32_fp8(bb.x, false);
            f32x2 p1 = __builtin_amdgcn_cvt_pk_f32_fp8(bb.x, true);
            f32x2 p2 = __builtin_amdgcn_cvt_pk_f32_fp8(bb.y, false);
            f32x2 p3 = __builtin_amdgcn_cvt_pk_f32_fp8(bb.y, true);
            acc[0] += ww * p0[0]; acc[1] += ww * p0[1];
            acc[2] += ww * p1[0]; acc[3] += ww * p1[1];
            acc[4] += ww * p2[0]; acc[5] += ww * p2[1];
            acc[6] += ww * p3[0]; acc[7] += ww * p3[1];
        }

        o[0] = h2f(xr[0]) + lrelu(acc[0] + bv0.x);
        o[1] = h2f(xr[1]) + lrelu(acc[1] + bv0.y);
        o[2] = h2f(xr[2]) + lrelu(acc[2] + bv0.z);
        o[3] = h2f(xr[3]) + lrelu(acc[3] + bv0.w);
        o[4] = h2f(xr[4]) + lrelu(acc[4] + bv1.x);
        o[5] = h2f(xr[5]) + lrelu(acc[5] + bv1.y);
        o[6] = h2f(xr[6]) + lrelu(acc[6] + bv1.z);
        o[7] = h2f(xr[7]) + lrelu(acc[7] + bv1.w);
    }

    // stash this node's 8 channels, then block-reduce 8 nodes -> 1 partial row
    #pragma unroll
    for (int c = 0; c < 8; c++) red[node][hl * 8 + c] = o[c];
    __syncthreads();
    int t = tid;
    float sum = 0.f;
    #pragma unroll
    for (int n = 0; n < 8; n++) sum += red[n][t];
    partial[(size_t)blockIdx.x * 256 + t] = sum;
}

// ---------- pooling tail (parallel tree: 16384 -> 512 -> 32 -> 2) + head ----------

__global__ void k_ptree(const float* __restrict__ in, float* __restrict__ out,
                        int rowsPerChunk) {
    int blk = blockIdx.x, t = threadIdx.x;
    size_t rowbase = (size_t)blk * rowsPerChunk;
    float s = 0.f;
    for (int j = 0; j < rowsPerChunk; j++)
        s += in[(rowbase + j) * 256 + t];
    out[(size_t)blk * 256 + t] = s;
}

__global__ void k_pool3(const float* __restrict__ partial2, float* __restrict__ pooled,
                        int chunksPerBatch, float inv) {
    int b = blockIdx.x, t = threadIdx.x;
    float s = 0.f;
    for (int j = 0; j < chunksPerBatch; j++)
        s += partial2[((size_t)b * chunksPerBatch + j) * 256 + t];
    pooled[b * 256 + t] = s * inv;
}

__global__ void k_head(const float* __restrict__ pooled, const float* __restrict__ Wh,
                       const float* __restrict__ bh, float* __restrict__ out) {
    int b = blockIdx.x, o = threadIdx.x;
    float acc = bh[o];
    for (int h = 0; h < H_DIM; h++) acc += pooled[b * H_DIM + h] * Wh[h * OUT_DIM + o];
    out[b * OUT_DIM + o] = acc;
}

// ---------- host ----------

extern "C" void kernel_launch(void* const* d_in, const int* in_sizes, int n_in,
                              void* d_out, int out_size, void* d_ws, size_t ws_size,
                              hipStream_t stream) {
    const float* sst  = (const float*)d_in[0];
    const int*   mask = (const int*)d_in[1];
    const int*   eidx = (const int*)d_in[2];
    const float* W1   = (const float*)d_in[3];
    const float* b1   = (const float*)d_in[4];
    const float* Ws   = (const float*)d_in[5];
    const float* bs   = (const float*)d_in[6];
    const float* Wh   = (const float*)d_in[7];
    const float* bh   = (const float*)d_in[8];

    const int B  = out_size / OUT_DIM;               // 2
    const int Nn = in_sizes[1];                      // 65536
    const int E  = in_sizes[2] / 2;                  // 1048576
    const int F  = in_sizes[0] / B;                  // 686364
    const int DEPTH = in_sizes[5] / (H_DIM * H_DIM); // 8
    const int NT = B * Nn;                           // 131072

    // workspace carve-up (256B aligned) — total ~140 MB
    size_t off = 0;
    char* base = (char*)d_ws;
    auto alloc = [&](size_t bytes) -> void* {
        void* p = base + off;
        off += (bytes + 255) & ~(size_t)255;
        return p;
    };
    ushort_t*      xh      = (ushort_t*)alloc((size_t)NT * H_DIM * 2);  // 67.1 MB fp16 residual
    unsigned char* zbuf    = (unsigned char*)alloc((size_t)NT * 256);   // 33.5 MB fp8
    float*    x0      = (float*)alloc((size_t)NT * 4);
    float*    y0      = (float*)alloc((size_t)NT * 4);
    int*      cnt     = (int*)alloc((size_t)NT * 4);
    int*      startp  = (int*)alloc((size_t)NT * 4);
    float*    dis     = (float*)alloc((size_t)NT * 4);
    int*      bsum    = (int*)alloc(4096);
    int*      bpre    = (int*)alloc(4096);
    int*      rank    = (int*)alloc((size_t)E * 4);                     // 4 MB
    int2*     ecsr    = (int2*)alloc((size_t)E * 8);                    // 8 MB
    ushort_t* Wt      = (ushort_t*)alloc((size_t)DEPTH * H_DIM * H_DIM * 2);  // 1 MB fp16
    float*    partial = (float*)alloc((size_t)(NT / 8) * 256 * 4);      // 16.8 MB
    float*    partialB= (float*)alloc((size_t)512 * 256 * 4);           // 512 KB
    float*    partial2= (float*)alloc((size_t)64 * 256 * 4);
    float*    pooled  = (float*)alloc((size_t)B * 256 * 4);
    if (off > ws_size) return;   // workspace too small: fail visibly

    const int* esrc = eidx;
    const int* edst = eidx + E;

    dim3 blk(256);
    int gNT = (NT + 255) / 256;
    int gE  = (E + 255) / 256;
    int nb  = gNT;               // 512 scan blocks

    hipMemsetAsync(cnt, 0, (size_t)NT * 4, stream);

    k_gather_x0<<<gNT, blk, 0, stream>>>(sst, mask, x0, NT, Nn, F);
    k_count<<<gE, blk, 0, stream>>>(edst, cnt, rank, E);
    k_dis<<<gNT, blk, 0, stream>>>(cnt, dis, NT);
    k_scan_block<<<nb, blk, 0, stream>>>(cnt, bsum, NT);
    k_scan_top<<<1, 512, 0, stream>>>(bsum, bpre, nb);
    k_scan_scatter<<<nb, blk, 0, stream>>>(cnt, bpre, startp, NT);
    k_fill<<<gE, blk, 0, stream>>>(esrc, edst, rank, startp, dis, ecsr, E);
    k_prepW<<<(DEPTH * H_DIM * H_DIM + 255) / 256, blk, 0, stream>>>(Ws, Wt, DEPTH * H_DIM * H_DIM);

    // layer 1: scalar -> H (fp16 residual stream)
    k_agg0<<<gNT, blk, 0, stream>>>(x0, startp, cnt, ecsr, dis, y0, NT);
    k_expand<<<(NT * 64 + 255) / 256, blk, 0, stream>>>(x0, y0, W1, b1, xh, NT);

    // layers 2..8: z = xh@W (fp8 out), then aggregate+bias+leaky+residual into xh
    for (int l = 0; l < DEPTH - 1; l++) {
        k_gemm<<<512, blk, 0, stream>>>(xh, Wt + (size_t)l * H_DIM * H_DIM, zbuf, NT);
        k_aggres<<<NT / 8, blk, 0, stream>>>(zbuf, startp, cnt, ecsr, dis,
                                             bs + (size_t)l * H_DIM, xh, NT);
    }
    // layer 9: fused aggregate + residual + block pooling (no xh write)
    {
        int l = DEPTH - 1;
        k_gemm<<<512, blk, 0, stream>>>(xh, Wt + (size_t)l * H_DIM * H_DIM, zbuf, NT);
        k_aggres_pool<<<NT / 8, blk, 0, stream>>>(zbuf, startp, cnt, ecsr, dis,
                                                  bs + (size_t)l * H_DIM, xh, partial, NT);
    }

    // pool tail: 16384 partial rows -> 512 -> 32 -> 2 (all stages parallel)
    int pblocks = NT / 8;                  // 16384
    k_ptree<<<512, blk, 0, stream>>>(partial, partialB, pblocks / 512);     // 32 rows each
    k_ptree<<<32, blk, 0, stream>>>(partialB, partial2, 16);                // 16 rows each
    k_pool3<<<B, blk, 0, stream>>>(partial2, pooled, 32 / B, 1.0f / (float)Nn);
    k_head<<<B, blk, 0, stream>>>(pooled, Wh, bh, (float*)d_out);
}

// Round 18
// 775.656 us; speedup vs baseline: 1.2080x; 1.0751x over previous
//
#include <hip/hip_runtime.h>

typedef unsigned short ushort_t;
typedef _Float16 f16x8 __attribute__((ext_vector_type(8)));
typedef float f32x4 __attribute__((ext_vector_type(4)));
typedef float f32x2 __attribute__((ext_vector_type(2)));
typedef unsigned short us8 __attribute__((ext_vector_type(8)));

#define H_DIM 256
#define OUT_DIM 256

__device__ inline float lrelu(float v) { return v > 0.f ? v : 0.01f * v; }

__device__ inline unsigned short f2h(float f) {
    _Float16 h = (_Float16)f;
    unsigned short u;
    __builtin_memcpy(&u, &h, 2);
    return u;
}

// ---------- prep kernels ----------

__global__ void k_gather_x0(const float* __restrict__ sst, const int* __restrict__ mask,
                            float* __restrict__ x0, int NT, int Nn, int F) {
    int v = blockIdx.x * 256 + threadIdx.x;
    if (v < NT) {
        int b = v / Nn;
        int i = v - b * Nn;
        x0[v] = sst[(size_t)b * F + mask[i]];
    }
}

// count + record each edge's rank within its dst bucket (coalesced store)
__global__ void k_count(const int* __restrict__ dst, int* __restrict__ cnt,
                        int* __restrict__ rank, int E) {
    int e = blockIdx.x * 256 + threadIdx.x;
    if (e < E) rank[e] = atomicAdd(&cnt[dst[e]], 1);
}

__global__ void k_dis(const int* __restrict__ cnt, float* __restrict__ dis, int NT) {
    int v = blockIdx.x * 256 + threadIdx.x;
    if (v < NT) dis[v] = rsqrtf((float)cnt[v] + 1.0f);
}

__global__ void k_scan_block(const int* __restrict__ cnt, int* __restrict__ bsum, int NT) {
    __shared__ int s[256];
    int i = blockIdx.x * 256 + threadIdx.x;
    s[threadIdx.x] = (i < NT) ? cnt[i] : 0;
    __syncthreads();
    for (int o = 128; o > 0; o >>= 1) {
        if (threadIdx.x < o) s[threadIdx.x] += s[threadIdx.x + o];
        __syncthreads();
    }
    if (threadIdx.x == 0) bsum[blockIdx.x] = s[0];
}

__global__ void k_scan_top(const int* __restrict__ bsum, int* __restrict__ bpre, int nb) {
    __shared__ int s[512];
    int t = threadIdx.x;
    int v = (t < nb) ? bsum[t] : 0;
    s[t] = v;
    __syncthreads();
    for (int o = 1; o < nb; o <<= 1) {
        int add = (t >= o) ? s[t - o] : 0;
        __syncthreads();
        s[t] += add;
        __syncthreads();
    }
    if (t < nb) bpre[t] = s[t] - v;   // exclusive
}

__global__ void k_scan_scatter(const int* __restrict__ cnt, const int* __restrict__ bpre,
                               int* __restrict__ startp, int NT) {
    __shared__ int s[256];
    int t = threadIdx.x;
    int i = blockIdx.x * 256 + t;
    int v = (i < NT) ? cnt[i] : 0;
    s[t] = v;
    __syncthreads();
    for (int o = 1; o < 256; o <<= 1) {
        int add = (t >= o) ? s[t - o] : 0;
        __syncthreads();
        s[t] += add;
        __syncthreads();
    }
    int excl = s[t] - v + bpre[blockIdx.x];
    if (i < NT) startp[i] = excl;
}

// fill: atomic-free; one packed 8B store per edge {src, cnorm bits}
__global__ void k_fill(const int* __restrict__ src, const int* __restrict__ dst,
                       const int* __restrict__ rank, const int* __restrict__ startp,
                       const float* __restrict__ dis, int2* __restrict__ ecsr, int E) {
    int e = blockIdx.x * 256 + threadIdx.x;
    if (e < E) {
        int s = src[e], d = dst[e];
        float nw = dis[s] * dis[d];
        int p = startp[d] + rank[e];
        ecsr[p] = make_int2(s, __float_as_int(nw));
    }
}

__global__ void k_prepW(const float* __restrict__ Ws, ushort_t* __restrict__ Wt, int total) {
    int idx = blockIdx.x * 256 + threadIdx.x;
    if (idx < total) {
        int l = idx >> 16;          // layer
        int rem = idx & 65535;
        int k = rem >> 8;           // input dim
        int n = rem & 255;          // output dim
        Wt[(l << 16) + (n << 8) + k] = f2h(Ws[idx]);
    }
}

// ---------- layer 1 (scalar input) ----------

__global__ void k_agg0(const float* __restrict__ x0, const int* __restrict__ startp,
                       const int* __restrict__ cnt, const int2* __restrict__ ecsr,
                       const float* __restrict__ dis, float* __restrict__ y0, int NT) {
    int v = blockIdx.x * 256 + threadIdx.x;
    if (v >= NT) return;
    float d = dis[v];
    float acc = d * d * x0[v];
    int s = startp[v], e = s + cnt[v];
    for (int i = s; i < e; i++) {
        int2 ec = ecsr[i];
        acc += __int_as_float(ec.y) * x0[ec.x];
    }
    y0[v] = acc;
}

// expand: write fp8 residual stream (4 channels = 1 uint per thread)
__global__ void k_expand(const float* __restrict__ x0, const float* __restrict__ y0,
                         const float* __restrict__ W1, const float* __restrict__ b1,
                         unsigned int* __restrict__ xh8, int NT) {
    int idx = blockIdx.x * 256 + threadIdx.x;      // NT*64 threads
    int v = idx >> 6;
    int q = idx & 63;
    if (v >= NT) return;
    float xv = x0[v], yv = y0[v];
    float4 w = ((const float4*)W1)[q];
    float4 b = ((const float4*)b1)[q];
    float o0 = xv + lrelu(yv * w.x + b.x);
    float o1 = xv + lrelu(yv * w.y + b.y);
    float o2 = xv + lrelu(yv * w.z + b.z);
    float o3 = xv + lrelu(yv * w.w + b.w);
    unsigned int r = 0;
    r = __builtin_amdgcn_cvt_pk_fp8_f32(o0, o1, r, false);
    r = __builtin_amdgcn_cvt_pk_fp8_f32(o2, o3, r, true);
    xh8[(size_t)v * 64 + q] = r;
}

// ---------- GEMM: z = xh8 @ W (fp8 A dequant->fp16 in staging; fp16 MFMA) ----------
// W fp16 in REGISTERS; A staged per 64-row tile with XOR-swizzled fp16 LDS.
// Block: 256 thr = 4 waves; grid-stride. One barrier pair per tile.

__global__ __launch_bounds__(256) void k_gemm(const unsigned char* __restrict__ xh8,
                                              const ushort_t* __restrict__ Wt,
                                              unsigned char* __restrict__ z, int NT) {
    __shared__ __align__(16) char AsRaw[64 * 512];    // 32 KB: 64 rows x 256 fp16 (swizzled)
    __shared__ __align__(16) char Rep[4][4096];       // 16 KB: per-wave fp8 repack
    int tid = threadIdx.x;
    int wave = tid >> 6, lane = tid & 63;
    int rl = lane & 15, hi = lane >> 4;               // hi in 0..3

    // ---- W fragments into registers: wave owns n-cols [wave*64, +64) ----
    f16x8 bf[4][8];
    #pragma unroll
    for (int ni = 0; ni < 4; ni++)
        #pragma unroll
        for (int c = 0; c < 8; c++)
            bf[ni][c] = *(const f16x8*)(Wt + (size_t)(wave * 64 + ni * 16 + rl) * 256
                                        + c * 32 + hi * 8);

    int ntiles = NT / 64;
    for (int t = blockIdx.x; t < ntiles; t += gridDim.x) {
        size_t rowbase = (size_t)t * 64;

        // ---- stage A tile: 64 rows x 256 fp8 -> fp16 LDS, swizzled write ----
        // 2048 chunks of 8 fp8 (8B load -> 16B fp16 store), 8 passes
        #pragma unroll
        for (int p = 0; p < 8; p++) {
            int idx = p * 256 + tid;
            int row = idx >> 5;
            int c8 = idx & 31;                         // chunk of 8 channels
            uint2 srcv = *(const uint2*)(xh8 + (rowbase + row) * 256 + c8 * 8);
            f32x2 a0 = __builtin_amdgcn_cvt_pk_f32_fp8(srcv.x, false);
            f32x2 a1 = __builtin_amdgcn_cvt_pk_f32_fp8(srcv.x, true);
            f32x2 a2 = __builtin_amdgcn_cvt_pk_f32_fp8(srcv.y, false);
            f32x2 a3 = __builtin_amdgcn_cvt_pk_f32_fp8(srcv.y, true);
            us8 o;
            o[0] = f2h(a0[0]); o[1] = f2h(a0[1]); o[2] = f2h(a1[0]); o[3] = f2h(a1[1]);
            o[4] = f2h(a2[0]); o[5] = f2h(a2[1]); o[6] = f2h(a3[0]); o[7] = f2h(a3[1]);
            int colb = c8 * 16;
            *(us8*)(AsRaw + row * 512 + (colb ^ ((row & 7) << 4))) = o;
        }
        __syncthreads();

        // ---- MFMA: 8 k-chunks x (4 mi x 4 ni) ----
        f32x4 acc[4][4];
        #pragma unroll
        for (int mi = 0; mi < 4; mi++)
            #pragma unroll
            for (int ni = 0; ni < 4; ni++)
                acc[mi][ni] = (f32x4){0.f, 0.f, 0.f, 0.f};

        #pragma unroll
        for (int c = 0; c < 8; c++) {
            f16x8 af[4];
            #pragma unroll
            for (int mi = 0; mi < 4; mi++) {
                int row = mi * 16 + rl;
                int colb = c * 64 + hi * 16;
                af[mi] = *(const f16x8*)(AsRaw + row * 512 + (colb ^ ((row & 7) << 4)));
            }
            #pragma unroll
            for (int mi = 0; mi < 4; mi++)
                #pragma unroll
                for (int ni = 0; ni < 4; ni++)
                    acc[mi][ni] = __builtin_amdgcn_mfma_f32_16x16x32_f16(
                        af[mi], bf[ni][c], acc[mi][ni], 0, 0, 0);
        }
        __syncthreads();   // As free for next tile's stage

        // ---- epilogue: fp8 pack -> per-wave LDS slice -> coalesced stores ----
        char* slice = &Rep[wave][0];
        #pragma unroll
        for (int mi = 0; mi < 4; mi++)
            #pragma unroll
            for (int ni = 0; ni < 4; ni++)
                #pragma unroll
                for (int r = 0; r < 4; r++) {
                    float vv = acc[mi][ni][r];
                    int pk = __builtin_amdgcn_cvt_pk_fp8_f32(vv, vv, 0, false);
                    slice[(mi * 16 + hi * 4 + r) * 64 + ni * 16 + rl] = (char)(pk & 0xFF);
                }
        #pragma unroll
        for (int p = 0; p < 4; p++) {
            uint4 val = *(const uint4*)(slice + p * 1024 + lane * 16);
            int lrow = p * 16 + (lane >> 2);
            int lcolb = (lane & 3) * 16;
            *(uint4*)(z + (rowbase + lrow) * 256 + wave * 64 + lcolb) = val;
        }
    }
}

// ---------- aggregate + bias + leaky + residual (in-place fp8 xh update) ----------
// TWO nodes per wave; half-wave (32 lanes x 8B) per 256B fp8 row.
// Metadata loaded once, shfl broadcast. Pipelined: prefetch next 4 rows during FMA.

__global__ void k_aggres(const unsigned char* __restrict__ z, const int* __restrict__ startp,
                         const int* __restrict__ cnt, const int2* __restrict__ ecsr,
                         const float* __restrict__ dis, const float* __restrict__ bias,
                         unsigned char* __restrict__ xh8, int NT) {
    int tid = threadIdx.x;
    int wave = tid >> 6, lane = tid & 63;
    int h = lane >> 5, hl = lane & 31;
    int v = blockIdx.x * 8 + wave * 2 + h;
    if (v >= NT) return;

    float d = dis[v];
    int s = startp[v], cv = cnt[v];

    int nsrc = 0;
    float nw = 0.f;
    if (hl < cv) {
        int2 ec = ecsr[s + hl];
        nsrc = ec.x;
        nw = __int_as_float(ec.y);
    }

    int cv0 = __shfl(cv, 0);
    int cv1 = __shfl(cv, 32);
    int cvmax = cv0 > cv1 ? cv0 : cv1;
    int inl = cvmax > 32 ? 32 : cvmax;
    int iters = (inl + 3) & ~3;

    uint2 a = *(const uint2*)(z + (size_t)v * 256 + hl * 8);
    uint2 xr8 = *(const uint2*)(xh8 + (size_t)v * 256 + hl * 8);
    float4 bv0 = *(const float4*)(bias + hl * 8);
    float4 bv1 = *(const float4*)(bias + hl * 8 + 4);

    float sn = d * d;
    float acc[8];
    {
        f32x2 p0 = __builtin_amdgcn_cvt_pk_f32_fp8(a.x, false);
        f32x2 p1 = __builtin_amdgcn_cvt_pk_f32_fp8(a.x, true);
        f32x2 p2 = __builtin_amdgcn_cvt_pk_f32_fp8(a.y, false);
        f32x2 p3 = __builtin_amdgcn_cvt_pk_f32_fp8(a.y, true);
        acc[0] = sn * p0[0]; acc[1] = sn * p0[1];
        acc[2] = sn * p1[0]; acc[3] = sn * p1[1];
        acc[4] = sn * p2[0]; acc[5] = sn * p2[1];
        acc[6] = sn * p3[0]; acc[7] = sn * p3[1];
    }

    int base = h << 5;
    uint2 b[4];
    float w[4];
    #pragma unroll
    for (int j = 0; j < 4; j++) {
        int ii = __shfl(nsrc, base + j);
        w[j]   = __shfl(nw,   base + j);
        b[j] = *(const uint2*)(z + (size_t)ii * 256 + hl * 8);
    }
    for (int k = 0; k < iters; k += 4) {
        uint2 nb[4];
        float nwt[4];
        bool more = (k + 4) < iters;
        if (more) {
            #pragma unroll
            for (int j = 0; j < 4; j++) {
                int ii = __shfl(nsrc, base + k + 4 + j);
                nwt[j] = __shfl(nw,   base + k + 4 + j);
                nb[j] = *(const uint2*)(z + (size_t)ii * 256 + hl * 8);
            }
        }
        #pragma unroll
        for (int j = 0; j < 4; j++) {
            f32x2 p0 = __builtin_amdgcn_cvt_pk_f32_fp8(b[j].x, false);
            f32x2 p1 = __builtin_amdgcn_cvt_pk_f32_fp8(b[j].x, true);
            f32x2 p2 = __builtin_amdgcn_cvt_pk_f32_fp8(b[j].y, false);
            f32x2 p3 = __builtin_amdgcn_cvt_pk_f32_fp8(b[j].y, true);
            float ww = w[j];
            acc[0] += ww * p0[0]; acc[1] += ww * p0[1];
            acc[2] += ww * p1[0]; acc[3] += ww * p1[1];
            acc[4] += ww * p2[0]; acc[5] += ww * p2[1];
            acc[6] += ww * p3[0]; acc[7] += ww * p3[1];
        }
        if (more) {
            #pragma unroll
            for (int j = 0; j < 4; j++) { b[j] = nb[j]; w[j] = nwt[j]; }
        }
    }
    for (int k = 32; k < cv; k++) {
        int2 ec = ecsr[s + k];
        float ww = __int_as_float(ec.y);
        uint2 bb = *(const uint2*)(z + (size_t)ec.x * 256 + hl * 8);
        f32x2 p0 = __builtin_amdgcn_cvt_pk_f32_fp8(bb.x, false);
        f32x2 p1 = __builtin_amdgcn_cvt_pk_f32_fp8(bb.x, true);
        f32x2 p2 = __builtin_amdgcn_cvt_pk_f32_fp8(bb.y, false);
        f32x2 p3 = __builtin_amdgcn_cvt_pk_f32_fp8(bb.y, true);
        acc[0] += ww * p0[0]; acc[1] += ww * p0[1];
        acc[2] += ww * p1[0]; acc[3] += ww * p1[1];
        acc[4] += ww * p2[0]; acc[5] += ww * p2[1];
        acc[6] += ww * p3[0]; acc[7] += ww * p3[1];
    }

    f32x2 x0_ = __builtin_amdgcn_cvt_pk_f32_fp8(xr8.x, false);
    f32x2 x1_ = __builtin_amdgcn_cvt_pk_f32_fp8(xr8.x, true);
    f32x2 x2_ = __builtin_amdgcn_cvt_pk_f32_fp8(xr8.y, false);
    f32x2 x3_ = __builtin_amdgcn_cvt_pk_f32_fp8(xr8.y, true);
    float o0 = x0_[0] + lrelu(acc[0] + bv0.x);
    float o1 = x0_[1] + lrelu(acc[1] + bv0.y);
    float o2 = x1_[0] + lrelu(acc[2] + bv0.z);
    float o3 = x1_[1] + lrelu(acc[3] + bv0.w);
    float o4 = x2_[0] + lrelu(acc[4] + bv1.x);
    float o5 = x2_[1] + lrelu(acc[5] + bv1.y);
    float o6 = x3_[0] + lrelu(acc[6] + bv1.z);
    float o7 = x3_[1] + lrelu(acc[7] + bv1.w);
    uint2 w8;
    w8.x = __builtin_amdgcn_cvt_pk_fp8_f32(o0, o1, 0, false);
    w8.x = __builtin_amdgcn_cvt_pk_fp8_f32(o2, o3, w8.x, true);
    w8.y = __builtin_amdgcn_cvt_pk_fp8_f32(o4, o5, 0, false);
    w8.y = __builtin_amdgcn_cvt_pk_fp8_f32(o6, o7, w8.y, true);
    *(uint2*)(xh8 + (size_t)v * 256 + hl * 8) = w8;
}

// ---------- FINAL layer: aggregate + residual, fused block-level pooling ----------

__global__ void k_aggres_pool(const unsigned char* __restrict__ z, const int* __restrict__ startp,
                              const int* __restrict__ cnt, const int2* __restrict__ ecsr,
                              const float* __restrict__ dis, const float* __restrict__ bias,
                              const unsigned char* __restrict__ xh8, float* __restrict__ partial,
                              int NT) {
    __shared__ float red[8][256];
    int tid = threadIdx.x;
    int wave = tid >> 6, lane = tid & 63;
    int h = lane >> 5, hl = lane & 31;
    int node = wave * 2 + h;               // 0..7 within block
    int v = blockIdx.x * 8 + node;

    float o[8];
    #pragma unroll
    for (int c = 0; c < 8; c++) o[c] = 0.f;

    if (v < NT) {
        float d = dis[v];
        int s = startp[v], cv = cnt[v];

        int nsrc = 0;
        float nw = 0.f;
        if (hl < cv) {
            int2 ec = ecsr[s + hl];
            nsrc = ec.x;
            nw = __int_as_float(ec.y);
        }

        int cv0 = __shfl(cv, 0);
        int cv1 = __shfl(cv, 32);
        int cvmax = cv0 > cv1 ? cv0 : cv1;
        int inl = cvmax > 32 ? 32 : cvmax;
        int iters = (inl + 3) & ~3;

        uint2 a = *(const uint2*)(z + (size_t)v * 256 + hl * 8);
        uint2 xr8 = *(const uint2*)(xh8 + (size_t)v * 256 + hl * 8);
        float4 bv0 = *(const float4*)(bias + hl * 8);
        float4 bv1 = *(const float4*)(bias + hl * 8 + 4);

        float sn = d * d;
        float acc[8];
        {
            f32x2 p0 = __builtin_amdgcn_cvt_pk_f32_fp8(a.x, false);
            f32x2 p1 = __builtin_amdgcn_cvt_pk_f32_fp8(a.x, true);
            f32x2 p2 = __builtin_amdgcn_cvt_pk_f32_fp8(a.y, false);
            f32x2 p3 = __builtin_amdgcn_cvt_pk_f32_fp8(a.y, true);
            acc[0] = sn * p0[0]; acc[1] = sn * p0[1];
            acc[2] = sn * p1[0]; acc[3] = sn * p1[1];
            acc[4] = sn * p2[0]; acc[5] = sn * p2[1];
            acc[6] = sn * p3[0]; acc[7] = sn * p3[1];
        }

        int base = h << 5;
        uint2 b[4];
        float w[4];
        #pragma unroll
        for (int j = 0; j < 4; j++) {
            int ii = __shfl(nsrc, base + j);
            w[j]   = __shfl(nw,   base + j);
            b[j] = *(const uint2*)(z + (size_t)ii * 256 + hl * 8);
        }
        for (int k = 0; k < iters; k += 4) {
            uint2 nb[4];
            float nwt[4];
            bool more = (k + 4) < iters;
            if (more) {
                #pragma unroll
                for (int j = 0; j < 4; j++) {
                    int ii = __shfl(nsrc, base + k + 4 + j);
                    nwt[j] = __shfl(nw,   base + k + 4 + j);
                    nb[j] = *(const uint2*)(z + (size_t)ii * 256 + hl * 8);
                }
            }
            #pragma unroll
            for (int j = 0; j < 4; j++) {
                f32x2 p0 = __builtin_amdgcn_cvt_pk_f32_fp8(b[j].x, false);
                f32x2 p1 = __builtin_amdgcn_cvt_pk_f32_fp8(b[j].x, true);
                f32x2 p2 = __builtin_amdgcn_cvt_pk_f32_fp8(b[j].y, false);
                f32x2 p3 = __builtin_amdgcn_cvt_pk_f32_fp8(b[j].y, true);
                float ww = w[j];
                acc[0] += ww * p0[0]; acc[1] += ww * p0[1];
                acc[2] += ww * p1[0]; acc[3] += ww * p1[1];
                acc[4] += ww * p2[0]; acc[5] += ww * p2[1];
                acc[6] += ww * p3[0]; acc[7] += ww * p3[1];
            }
            if (more) {
                #pragma unroll
                for (int j = 0; j < 4; j++) { b[j] = nb[j]; w[j] = nwt[j]; }
            }
        }
        for (int k = 32; k < cv; k++) {
            int2 ec = ecsr[s + k];
            float ww = __int_as_float(ec.y);
            uint2 bb = *(const uint2*)(z + (size_t)ec.x * 256 + hl * 8);
            f32x2 p0 = __builtin_amdgcn_cvt_pk_f32_fp8(bb.x, false);
            f32x2 p1 = __builtin_amdgcn_cvt_pk_f32_fp8(bb.x, true);
            f32x2 p2 = __builtin_amdgcn_cvt_pk_f32_fp8(bb.y, false);
            f32x2 p3 = __builtin_amdgcn_cvt_pk_f32_fp8(bb.y, true);
            acc[0] += ww * p0[0]; acc[1] += ww * p0[1];
            acc[2] += ww * p1[0]; acc[3] += ww * p1[1];
            acc[4] += ww * p2[0]; acc[5] += ww * p2[1];
            acc[6] += ww * p3[0]; acc[7] += ww * p3[1];
        }

        f32x2 x0_ = __builtin_amdgcn_cvt_pk_f32_fp8(xr8.x, false);
        f32x2 x1_ = __builtin_amdgcn_cvt_pk_f32_fp8(xr8.x, true);
        f32x2 x2_ = __builtin_amdgcn_cvt_pk_f32_fp8(xr8.y, false);
        f32x2 x3_ = __builtin_amdgcn_cvt_pk_f32_fp8(xr8.y, true);
        o[0] = x0_[0] + lrelu(acc[0] + bv0.x);
        o[1] = x0_[1] + lrelu(acc[1] + bv0.y);
        o[2] = x1_[0] + lrelu(acc[2] + bv0.z);
        o[3] = x1_[1] + lrelu(acc[3] + bv0.w);
        o[4] = x2_[0] + lrelu(acc[4] + bv1.x);
        o[5] = x2_[1] + lrelu(acc[5] + bv1.y);
        o[6] = x3_[0] + lrelu(acc[6] + bv1.z);
        o[7] = x3_[1] + lrelu(acc[7] + bv1.w);
    }

    // stash this node's 8 channels, then block-reduce 8 nodes -> 1 partial row
    #pragma unroll
    for (int c = 0; c < 8; c++) red[node][hl * 8 + c] = o[c];
    __syncthreads();
    int t = tid;
    float sum = 0.f;
    #pragma unroll
    for (int n = 0; n < 8; n++) sum += red[n][t];
    partial[(size_t)blockIdx.x * 256 + t] = sum;
}

// ---------- pooling tail (parallel tree: 16384 -> 512 -> 32 -> 2) + head ----------

__global__ void k_ptree(const float* __restrict__ in, float* __restrict__ out,
                        int rowsPerChunk) {
    int blk = blockIdx.x, t = threadIdx.x;
    size_t rowbase = (size_t)blk * rowsPerChunk;
    float s = 0.f;
    for (int j = 0; j < rowsPerChunk; j++)
        s += in[(rowbase + j) * 256 + t];
    out[(size_t)blk * 256 + t] = s;
}

__global__ void k_pool3(const float* __restrict__ partial2, float* __restrict__ pooled,
                        int chunksPerBatch, float inv) {
    int b = blockIdx.x, t = threadIdx.x;
    float s = 0.f;
    for (int j = 0; j < chunksPerBatch; j++)
        s += partial2[((size_t)b * chunksPerBatch + j) * 256 + t];
    pooled[b * 256 + t] = s * inv;
}

__global__ void k_head(const float* __restrict__ pooled, const float* __restrict__ Wh,
                       const float* __restrict__ bh, float* __restrict__ out) {
    int b = blockIdx.x, o = threadIdx.x;
    float acc = bh[o];
    for (int h = 0; h < H_DIM; h++) acc += pooled[b * H_DIM + h] * Wh[h * OUT_DIM + o];
    out[b * OUT_DIM + o] = acc;
}

// ---------- host ----------

extern "C" void kernel_launch(void* const* d_in, const int* in_sizes, int n_in,
                              void* d_out, int out_size, void* d_ws, size_t ws_size,
                              hipStream_t stream) {
    const float* sst  = (const float*)d_in[0];
    const int*   mask = (const int*)d_in[1];
    const int*   eidx = (const int*)d_in[2];
    const float* W1   = (const float*)d_in[3];
    const float* b1   = (const float*)d_in[4];
    const float* Ws   = (const float*)d_in[5];
    const float* bs   = (const float*)d_in[6];
    const float* Wh   = (const float*)d_in[7];
    const float* bh   = (const float*)d_in[8];

    const int B  = out_size / OUT_DIM;               // 2
    const int Nn = in_sizes[1];                      // 65536
    const int E  = in_sizes[2] / 2;                  // 1048576
    const int F  = in_sizes[0] / B;                  // 686364
    const int DEPTH = in_sizes[5] / (H_DIM * H_DIM); // 8
    const int NT = B * Nn;                           // 131072

    // workspace carve-up (256B aligned) — total ~107 MB
    size_t off = 0;
    char* base = (char*)d_ws;
    auto alloc = [&](size_t bytes) -> void* {
        void* p = base + off;
        off += (bytes + 255) & ~(size_t)255;
        return p;
    };
    unsigned char* xh8     = (unsigned char*)alloc((size_t)NT * 256);   // 33.5 MB fp8 residual
    unsigned char* zbuf    = (unsigned char*)alloc((size_t)NT * 256);   // 33.5 MB fp8
    float*    x0      = (float*)alloc((size_t)NT * 4);
    float*    y0      = (float*)alloc((size_t)NT * 4);
    int*      cnt     = (int*)alloc((size_t)NT * 4);
    int*      startp  = (int*)alloc((size_t)NT * 4);
    float*    dis     = (float*)alloc((size_t)NT * 4);
    int*      bsum    = (int*)alloc(4096);
    int*      bpre    = (int*)alloc(4096);
    int*      rank    = (int*)alloc((size_t)E * 4);                     // 4 MB
    int2*     ecsr    = (int2*)alloc((size_t)E * 8);                    // 8 MB
    ushort_t* Wt      = (ushort_t*)alloc((size_t)DEPTH * H_DIM * H_DIM * 2);  // 1 MB fp16
    float*    partial = (float*)alloc((size_t)(NT / 8) * 256 * 4);      // 16.8 MB
    float*    partialB= (float*)alloc((size_t)512 * 256 * 4);           // 512 KB
    float*    partial2= (float*)alloc((size_t)64 * 256 * 4);
    float*    pooled  = (float*)alloc((size_t)B * 256 * 4);
    if (off > ws_size) return;   // workspace too small: fail visibly

    const int* esrc = eidx;
    const int* edst = eidx + E;

    dim3 blk(256);
    int gNT = (NT + 255) / 256;
    int gE  = (E + 255) / 256;
    int nb  = gNT;               // 512 scan blocks

    hipMemsetAsync(cnt, 0, (size_t)NT * 4, stream);

    k_gather_x0<<<gNT, blk, 0, stream>>>(sst, mask, x0, NT, Nn, F);
    k_count<<<gE, blk, 0, stream>>>(edst, cnt, rank, E);
    k_dis<<<gNT, blk, 0, stream>>>(cnt, dis, NT);
    k_scan_block<<<nb, blk, 0, stream>>>(cnt, bsum, NT);
    k_scan_top<<<1, 512, 0, stream>>>(bsum, bpre, nb);
    k_scan_scatter<<<nb, blk, 0, stream>>>(cnt, bpre, startp, NT);
    k_fill<<<gE, blk, 0, stream>>>(esrc, edst, rank, startp, dis, ecsr, E);
    k_prepW<<<(DEPTH * H_DIM * H_DIM + 255) / 256, blk, 0, stream>>>(Ws, Wt, DEPTH * H_DIM * H_DIM);

    // layer 1: scalar -> H (fp8 residual stream)
    k_agg0<<<gNT, blk, 0, stream>>>(x0, startp, cnt, ecsr, dis, y0, NT);
    k_expand<<<(NT * 64 + 255) / 256, blk, 0, stream>>>(x0, y0, W1, b1,
                                                        (unsigned int*)xh8, NT);

    // layers 2..8: z = xh8@W (fp8 out), then aggregate+bias+leaky+residual into xh8
    for (int l = 0; l < DEPTH - 1; l++) {
        k_gemm<<<512, blk, 0, stream>>>(xh8, Wt + (size_t)l * H_DIM * H_DIM, zbuf, NT);
        k_aggres<<<NT / 8, blk, 0, stream>>>(zbuf, startp, cnt, ecsr, dis,
                                             bs + (size_t)l * H_DIM, xh8, NT);
    }
    // layer 9: fused aggregate + residual + block pooling (no xh write)
    {
        int l = DEPTH - 1;
        k_gemm<<<512, blk, 0, stream>>>(xh8, Wt + (size_t)l * H_DIM * H_DIM, zbuf, NT);
        k_aggres_pool<<<NT / 8, blk, 0, stream>>>(zbuf, startp, cnt, ecsr, dis,
                                                  bs + (size_t)l * H_DIM, xh8, partial, NT);
    }

    // pool tail: 16384 partial rows -> 512 -> 32 -> 2 (all stages parallel)
    int pblocks = NT / 8;                  // 16384
    k_ptree<<<512, blk, 0, stream>>>(partial, partialB, pblocks / 512);     // 32 rows each
    k_ptree<<<32, blk, 0, stream>>>(partialB, partial2, 16);                // 16 rows each
    k_pool3<<<B, blk, 0, stream>>>(partial2, pooled, 32 / B, 1.0f / (float)Nn);
    k_head<<<B, blk, 0, stream>>>(pooled, Wh, bh, (float*)d_out);
}

// Round 19
// 768.482 us; speedup vs baseline: 1.2193x; 1.0093x over previous
//
#include <hip/hip_runtime.h>

typedef unsigned short ushort_t;
typedef _Float16 f16x8 __attribute__((ext_vector_type(8)));
typedef float f32x4 __attribute__((ext_vector_type(4)));
typedef float f32x2 __attribute__((ext_vector_type(2)));
typedef unsigned short us8 __attribute__((ext_vector_type(8)));

#define H_DIM 256
#define OUT_DIM 256

__device__ inline float lrelu(float v) { return v > 0.f ? v : 0.01f * v; }

__device__ inline unsigned short f2h(float f) {
    _Float16 h = (_Float16)f;
    unsigned short u;
    __builtin_memcpy(&u, &h, 2);
    return u;
}

// ---------- prep kernels ----------

__global__ void k_gather_x0(const float* __restrict__ sst, const int* __restrict__ mask,
                            float* __restrict__ x0, int NT, int Nn, int F) {
    int v = blockIdx.x * 256 + threadIdx.x;
    if (v < NT) {
        int b = v / Nn;
        int i = v - b * Nn;
        x0[v] = sst[(size_t)b * F + mask[i]];
    }
}

// count + record each edge's rank within its dst bucket (coalesced store)
__global__ void k_count(const int* __restrict__ dst, int* __restrict__ cnt,
                        int* __restrict__ rank, int E) {
    int e = blockIdx.x * 256 + threadIdx.x;
    if (e < E) rank[e] = atomicAdd(&cnt[dst[e]], 1);
}

__global__ void k_dis(const int* __restrict__ cnt, float* __restrict__ dis, int NT) {
    int v = blockIdx.x * 256 + threadIdx.x;
    if (v < NT) dis[v] = rsqrtf((float)cnt[v] + 1.0f);
}

__global__ void k_scan_block(const int* __restrict__ cnt, int* __restrict__ bsum, int NT) {
    __shared__ int s[256];
    int i = blockIdx.x * 256 + threadIdx.x;
    s[threadIdx.x] = (i < NT) ? cnt[i] : 0;
    __syncthreads();
    for (int o = 128; o > 0; o >>= 1) {
        if (threadIdx.x < o) s[threadIdx.x] += s[threadIdx.x + o];
        __syncthreads();
    }
    if (threadIdx.x == 0) bsum[blockIdx.x] = s[0];
}

__global__ void k_scan_top(const int* __restrict__ bsum, int* __restrict__ bpre, int nb) {
    __shared__ int s[512];
    int t = threadIdx.x;
    int v = (t < nb) ? bsum[t] : 0;
    s[t] = v;
    __syncthreads();
    for (int o = 1; o < nb; o <<= 1) {
        int add = (t >= o) ? s[t - o] : 0;
        __syncthreads();
        s[t] += add;
        __syncthreads();
    }
    if (t < nb) bpre[t] = s[t] - v;   // exclusive
}

__global__ void k_scan_scatter(const int* __restrict__ cnt, const int* __restrict__ bpre,
                               int* __restrict__ startp, int NT) {
    __shared__ int s[256];
    int t = threadIdx.x;
    int i = blockIdx.x * 256 + t;
    int v = (i < NT) ? cnt[i] : 0;
    s[t] = v;
    __syncthreads();
    for (int o = 1; o < 256; o <<= 1) {
        int add = (t >= o) ? s[t - o] : 0;
        __syncthreads();
        s[t] += add;
        __syncthreads();
    }
    int excl = s[t] - v + bpre[blockIdx.x];
    if (i < NT) startp[i] = excl;
}

// fill: atomic-free; one packed 8B store per edge {src, cnorm bits}
__global__ void k_fill(const int* __restrict__ src, const int* __restrict__ dst,
                       const int* __restrict__ rank, const int* __restrict__ startp,
                       const float* __restrict__ dis, int2* __restrict__ ecsr, int E) {
    int e = blockIdx.x * 256 + threadIdx.x;
    if (e < E) {
        int s = src[e], d = dst[e];
        float nw = dis[s] * dis[d];
        int p = startp[d] + rank[e];
        ecsr[p] = make_int2(s, __float_as_int(nw));
    }
}

__global__ void k_prepW(const float* __restrict__ Ws, ushort_t* __restrict__ Wt, int total) {
    int idx = blockIdx.x * 256 + threadIdx.x;
    if (idx < total) {
        int l = idx >> 16;          // layer
        int rem = idx & 65535;
        int k = rem >> 8;           // input dim
        int n = rem & 255;          // output dim
        Wt[(l << 16) + (n << 8) + k] = f2h(Ws[idx]);
    }
}

// ---------- layer 1 (scalar input) ----------

__global__ void k_agg0(const float* __restrict__ x0, const int* __restrict__ startp,
                       const int* __restrict__ cnt, const int2* __restrict__ ecsr,
                       const float* __restrict__ dis, float* __restrict__ y0, int NT) {
    int v = blockIdx.x * 256 + threadIdx.x;
    if (v >= NT) return;
    float d = dis[v];
    float acc = d * d * x0[v];
    int s = startp[v], e = s + cnt[v];
    for (int i = s; i < e; i++) {
        int2 ec = ecsr[i];
        acc += __int_as_float(ec.y) * x0[ec.x];
    }
    y0[v] = acc;
}

// expand: write fp8 residual stream (4 channels = 1 uint per thread)
__global__ void k_expand(const float* __restrict__ x0, const float* __restrict__ y0,
                         const float* __restrict__ W1, const float* __restrict__ b1,
                         unsigned int* __restrict__ xh8, int NT) {
    int idx = blockIdx.x * 256 + threadIdx.x;      // NT*64 threads
    int v = idx >> 6;
    int q = idx & 63;
    if (v >= NT) return;
    float xv = x0[v], yv = y0[v];
    float4 w = ((const float4*)W1)[q];
    float4 b = ((const float4*)b1)[q];
    float o0 = xv + lrelu(yv * w.x + b.x);
    float o1 = xv + lrelu(yv * w.y + b.y);
    float o2 = xv + lrelu(yv * w.z + b.z);
    float o3 = xv + lrelu(yv * w.w + b.w);
    unsigned int r = 0;
    r = __builtin_amdgcn_cvt_pk_fp8_f32(o0, o1, r, false);
    r = __builtin_amdgcn_cvt_pk_fp8_f32(o2, o3, r, true);
    xh8[(size_t)v * 64 + q] = r;
}

// ---------- GEMM: z = xh8 @ W (fp8 A dequant->fp16 in staging; fp16 MFMA) ----------
// W fp16 in REGISTERS; A staged per 64-row tile with XOR-swizzled fp16 LDS.
// Block: 256 thr = 4 waves; grid-stride. One barrier pair per tile.

__global__ __launch_bounds__(256) void k_gemm(const unsigned char* __restrict__ xh8,
                                              const ushort_t* __restrict__ Wt,
                                              unsigned char* __restrict__ z, int NT) {
    __shared__ __align__(16) char AsRaw[64 * 512];    // 32 KB: 64 rows x 256 fp16 (swizzled)
    __shared__ __align__(16) char Rep[4][4096];       // 16 KB: per-wave fp8 repack
    int tid = threadIdx.x;
    int wave = tid >> 6, lane = tid & 63;
    int rl = lane & 15, hi = lane >> 4;               // hi in 0..3

    // ---- W fragments into registers: wave owns n-cols [wave*64, +64) ----
    f16x8 bf[4][8];
    #pragma unroll
    for (int ni = 0; ni < 4; ni++)
        #pragma unroll
        for (int c = 0; c < 8; c++)
            bf[ni][c] = *(const f16x8*)(Wt + (size_t)(wave * 64 + ni * 16 + rl) * 256
                                        + c * 32 + hi * 8);

    int ntiles = NT / 64;
    for (int t = blockIdx.x; t < ntiles; t += gridDim.x) {
        size_t rowbase = (size_t)t * 64;

        // ---- stage A tile: 64 rows x 256 fp8 -> fp16 LDS, swizzled write ----
        #pragma unroll
        for (int p = 0; p < 8; p++) {
            int idx = p * 256 + tid;
            int row = idx >> 5;
            int c8 = idx & 31;                         // chunk of 8 channels
            uint2 srcv = *(const uint2*)(xh8 + (rowbase + row) * 256 + c8 * 8);
            f32x2 a0 = __builtin_amdgcn_cvt_pk_f32_fp8(srcv.x, false);
            f32x2 a1 = __builtin_amdgcn_cvt_pk_f32_fp8(srcv.x, true);
            f32x2 a2 = __builtin_amdgcn_cvt_pk_f32_fp8(srcv.y, false);
            f32x2 a3 = __builtin_amdgcn_cvt_pk_f32_fp8(srcv.y, true);
            us8 o;
            o[0] = f2h(a0[0]); o[1] = f2h(a0[1]); o[2] = f2h(a1[0]); o[3] = f2h(a1[1]);
            o[4] = f2h(a2[0]); o[5] = f2h(a2[1]); o[6] = f2h(a3[0]); o[7] = f2h(a3[1]);
            int colb = c8 * 16;
            *(us8*)(AsRaw + row * 512 + (colb ^ ((row & 7) << 4))) = o;
        }
        __syncthreads();

        // ---- MFMA: 8 k-chunks x (4 mi x 4 ni) ----
        f32x4 acc[4][4];
        #pragma unroll
        for (int mi = 0; mi < 4; mi++)
            #pragma unroll
            for (int ni = 0; ni < 4; ni++)
                acc[mi][ni] = (f32x4){0.f, 0.f, 0.f, 0.f};

        #pragma unroll
        for (int c = 0; c < 8; c++) {
            f16x8 af[4];
            #pragma unroll
            for (int mi = 0; mi < 4; mi++) {
                int row = mi * 16 + rl;
                int colb = c * 64 + hi * 16;
                af[mi] = *(const f16x8*)(AsRaw + row * 512 + (colb ^ ((row & 7) << 4)));
            }
            #pragma unroll
            for (int mi = 0; mi < 4; mi++)
                #pragma unroll
                for (int ni = 0; ni < 4; ni++)
                    acc[mi][ni] = __builtin_amdgcn_mfma_f32_16x16x32_f16(
                        af[mi], bf[ni][c], acc[mi][ni], 0, 0, 0);
        }
        __syncthreads();   // As free for next tile's stage

        // ---- epilogue: fp8 pack -> per-wave LDS slice -> coalesced stores ----
        char* slice = &Rep[wave][0];
        #pragma unroll
        for (int mi = 0; mi < 4; mi++)
            #pragma unroll
            for (int ni = 0; ni < 4; ni++)
                #pragma unroll
                for (int r = 0; r < 4; r++) {
                    float vv = acc[mi][ni][r];
                    int pk = __builtin_amdgcn_cvt_pk_fp8_f32(vv, vv, 0, false);
                    slice[(mi * 16 + hi * 4 + r) * 64 + ni * 16 + rl] = (char)(pk & 0xFF);
                }
        #pragma unroll
        for (int p = 0; p < 4; p++) {
            uint4 val = *(const uint4*)(slice + p * 1024 + lane * 16);
            int lrow = p * 16 + (lane >> 2);
            int lcolb = (lane & 3) * 16;
            *(uint4*)(z + (rowbase + lrow) * 256 + wave * 64 + lcolb) = val;
        }
    }
}

// ---------- aggregate + bias + leaky + residual (in-place fp8 xh update) ----------
// TWO nodes per wave; half-wave (32 lanes x 8B) per 256B fp8 row.
// Packed f32x2 accumulators -> v_pk_fma_f32 (2 FMA/inst) on the dequant chain.

__global__ void k_aggres(const unsigned char* __restrict__ z, const int* __restrict__ startp,
                         const int* __restrict__ cnt, const int2* __restrict__ ecsr,
                         const float* __restrict__ dis, const float* __restrict__ bias,
                         unsigned char* __restrict__ xh8, int NT) {
    int tid = threadIdx.x;
    int wave = tid >> 6, lane = tid & 63;
    int h = lane >> 5, hl = lane & 31;
    int v = blockIdx.x * 8 + wave * 2 + h;
    if (v >= NT) return;

    float d = dis[v];
    int s = startp[v], cv = cnt[v];

    int nsrc = 0;
    float nw = 0.f;
    if (hl < cv) {
        int2 ec = ecsr[s + hl];
        nsrc = ec.x;
        nw = __int_as_float(ec.y);
    }

    int cv0 = __shfl(cv, 0);
    int cv1 = __shfl(cv, 32);
    int cvmax = cv0 > cv1 ? cv0 : cv1;
    int inl = cvmax > 32 ? 32 : cvmax;
    int iters = (inl + 3) & ~3;

    uint2 a = *(const uint2*)(z + (size_t)v * 256 + hl * 8);
    uint2 xr8 = *(const uint2*)(xh8 + (size_t)v * 256 + hl * 8);
    float4 bv0 = *(const float4*)(bias + hl * 8);
    float4 bv1 = *(const float4*)(bias + hl * 8 + 4);

    float sn = d * d;
    f32x2 snv = (f32x2){sn, sn};
    f32x2 acc01 = snv * __builtin_amdgcn_cvt_pk_f32_fp8(a.x, false);
    f32x2 acc23 = snv * __builtin_amdgcn_cvt_pk_f32_fp8(a.x, true);
    f32x2 acc45 = snv * __builtin_amdgcn_cvt_pk_f32_fp8(a.y, false);
    f32x2 acc67 = snv * __builtin_amdgcn_cvt_pk_f32_fp8(a.y, true);

    int base = h << 5;
    uint2 b[4];
    float w[4];
    #pragma unroll
    for (int j = 0; j < 4; j++) {
        int ii = __shfl(nsrc, base + j);
        w[j]   = __shfl(nw,   base + j);
        b[j] = *(const uint2*)(z + (size_t)ii * 256 + hl * 8);
    }
    for (int k = 0; k < iters; k += 4) {
        uint2 nb[4];
        float nwt[4];
        bool more = (k + 4) < iters;
        if (more) {
            #pragma unroll
            for (int j = 0; j < 4; j++) {
                int ii = __shfl(nsrc, base + k + 4 + j);
                nwt[j] = __shfl(nw,   base + k + 4 + j);
                nb[j] = *(const uint2*)(z + (size_t)ii * 256 + hl * 8);
            }
        }
        #pragma unroll
        for (int j = 0; j < 4; j++) {
            f32x2 wv = (f32x2){w[j], w[j]};
            acc01 += wv * __builtin_amdgcn_cvt_pk_f32_fp8(b[j].x, false);
            acc23 += wv * __builtin_amdgcn_cvt_pk_f32_fp8(b[j].x, true);
            acc45 += wv * __builtin_amdgcn_cvt_pk_f32_fp8(b[j].y, false);
            acc67 += wv * __builtin_amdgcn_cvt_pk_f32_fp8(b[j].y, true);
        }
        if (more) {
            #pragma unroll
            for (int j = 0; j < 4; j++) { b[j] = nb[j]; w[j] = nwt[j]; }
        }
    }
    for (int k = 32; k < cv; k++) {
        int2 ec = ecsr[s + k];
        float ww = __int_as_float(ec.y);
        f32x2 wv = (f32x2){ww, ww};
        uint2 bb = *(const uint2*)(z + (size_t)ec.x * 256 + hl * 8);
        acc01 += wv * __builtin_amdgcn_cvt_pk_f32_fp8(bb.x, false);
        acc23 += wv * __builtin_amdgcn_cvt_pk_f32_fp8(bb.x, true);
        acc45 += wv * __builtin_amdgcn_cvt_pk_f32_fp8(bb.y, false);
        acc67 += wv * __builtin_amdgcn_cvt_pk_f32_fp8(bb.y, true);
    }

    f32x2 x0_ = __builtin_amdgcn_cvt_pk_f32_fp8(xr8.x, false);
    f32x2 x1_ = __builtin_amdgcn_cvt_pk_f32_fp8(xr8.x, true);
    f32x2 x2_ = __builtin_amdgcn_cvt_pk_f32_fp8(xr8.y, false);
    f32x2 x3_ = __builtin_amdgcn_cvt_pk_f32_fp8(xr8.y, true);
    float o0 = x0_[0] + lrelu(acc01[0] + bv0.x);
    float o1 = x0_[1] + lrelu(acc01[1] + bv0.y);
    float o2 = x1_[0] + lrelu(acc23[0] + bv0.z);
    float o3 = x1_[1] + lrelu(acc23[1] + bv0.w);
    float o4 = x2_[0] + lrelu(acc45[0] + bv1.x);
    float o5 = x2_[1] + lrelu(acc45[1] + bv1.y);
    float o6 = x3_[0] + lrelu(acc67[0] + bv1.z);
    float o7 = x3_[1] + lrelu(acc67[1] + bv1.w);
    uint2 w8;
    w8.x = __builtin_amdgcn_cvt_pk_fp8_f32(o0, o1, 0, false);
    w8.x = __builtin_amdgcn_cvt_pk_fp8_f32(o2, o3, w8.x, true);
    w8.y = __builtin_amdgcn_cvt_pk_fp8_f32(o4, o5, 0, false);
    w8.y = __builtin_amdgcn_cvt_pk_fp8_f32(o6, o7, w8.y, true);
    *(uint2*)(xh8 + (size_t)v * 256 + hl * 8) = w8;
}

// ---------- FINAL layer: aggregate + residual, fused block-level pooling ----------

__global__ void k_aggres_pool(const unsigned char* __restrict__ z, const int* __restrict__ startp,
                              const int* __restrict__ cnt, const int2* __restrict__ ecsr,
                              const float* __restrict__ dis, const float* __restrict__ bias,
                              const unsigned char* __restrict__ xh8, float* __restrict__ partial,
                              int NT) {
    __shared__ float red[8][256];
    int tid = threadIdx.x;
    int wave = tid >> 6, lane = tid & 63;
    int h = lane >> 5, hl = lane & 31;
    int node = wave * 2 + h;               // 0..7 within block
    int v = blockIdx.x * 8 + node;

    float o[8];
    #pragma unroll
    for (int c = 0; c < 8; c++) o[c] = 0.f;

    if (v < NT) {
        float d = dis[v];
        int s = startp[v], cv = cnt[v];

        int nsrc = 0;
        float nw = 0.f;
        if (hl < cv) {
            int2 ec = ecsr[s + hl];
            nsrc = ec.x;
            nw = __int_as_float(ec.y);
        }

        int cv0 = __shfl(cv, 0);
        int cv1 = __shfl(cv, 32);
        int cvmax = cv0 > cv1 ? cv0 : cv1;
        int inl = cvmax > 32 ? 32 : cvmax;
        int iters = (inl + 3) & ~3;

        uint2 a = *(const uint2*)(z + (size_t)v * 256 + hl * 8);
        uint2 xr8 = *(const uint2*)(xh8 + (size_t)v * 256 + hl * 8);
        float4 bv0 = *(const float4*)(bias + hl * 8);
        float4 bv1 = *(const float4*)(bias + hl * 8 + 4);

        float sn = d * d;
        f32x2 snv = (f32x2){sn, sn};
        f32x2 acc01 = snv * __builtin_amdgcn_cvt_pk_f32_fp8(a.x, false);
        f32x2 acc23 = snv * __builtin_amdgcn_cvt_pk_f32_fp8(a.x, true);
        f32x2 acc45 = snv * __builtin_amdgcn_cvt_pk_f32_fp8(a.y, false);
        f32x2 acc67 = snv * __builtin_amdgcn_cvt_pk_f32_fp8(a.y, true);

        int base = h << 5;
        uint2 b[4];
        float w[4];
        #pragma unroll
        for (int j = 0; j < 4; j++) {
            int ii = __shfl(nsrc, base + j);
            w[j]   = __shfl(nw,   base + j);
            b[j] = *(const uint2*)(z + (size_t)ii * 256 + hl * 8);
        }
        for (int k = 0; k < iters; k += 4) {
            uint2 nb[4];
            float nwt[4];
            bool more = (k + 4) < iters;
            if (more) {
                #pragma unroll
                for (int j = 0; j < 4; j++) {
                    int ii = __shfl(nsrc, base + k + 4 + j);
                    nwt[j] = __shfl(nw,   base + k + 4 + j);
                    nb[j] = *(const uint2*)(z + (size_t)ii * 256 + hl * 8);
                }
            }
            #pragma unroll
            for (int j = 0; j < 4; j++) {
                f32x2 wv = (f32x2){w[j], w[j]};
                acc01 += wv * __builtin_amdgcn_cvt_pk_f32_fp8(b[j].x, false);
                acc23 += wv * __builtin_amdgcn_cvt_pk_f32_fp8(b[j].x, true);
                acc45 += wv * __builtin_amdgcn_cvt_pk_f32_fp8(b[j].y, false);
                acc67 += wv * __builtin_amdgcn_cvt_pk_f32_fp8(b[j].y, true);
            }
            if (more) {
                #pragma unroll
                for (int j = 0; j < 4; j++) { b[j] = nb[j]; w[j] = nwt[j]; }
            }
        }
        for (int k = 32; k < cv; k++) {
            int2 ec = ecsr[s + k];
            float ww = __int_as_float(ec.y);
            f32x2 wv = (f32x2){ww, ww};
            uint2 bb = *(const uint2*)(z + (size_t)ec.x * 256 + hl * 8);
            acc01 += wv * __builtin_amdgcn_cvt_pk_f32_fp8(bb.x, false);
            acc23 += wv * __builtin_amdgcn_cvt_pk_f32_fp8(bb.x, true);
            acc45 += wv * __builtin_amdgcn_cvt_pk_f32_fp8(bb.y, false);
            acc67 += wv * __builtin_amdgcn_cvt_pk_f32_fp8(bb.y, true);
        }

        f32x2 x0_ = __builtin_amdgcn_cvt_pk_f32_fp8(xr8.x, false);
        f32x2 x1_ = __builtin_amdgcn_cvt_pk_f32_fp8(xr8.x, true);
        f32x2 x2_ = __builtin_amdgcn_cvt_pk_f32_fp8(xr8.y, false);
        f32x2 x3_ = __builtin_amdgcn_cvt_pk_f32_fp8(xr8.y, true);
        o[0] = x0_[0] + lrelu(acc01[0] + bv0.x);
        o[1] = x0_[1] + lrelu(acc01[1] + bv0.y);
        o[2] = x1_[0] + lrelu(acc23[0] + bv0.z);
        o[3] = x1_[1] + lrelu(acc23[1] + bv0.w);
        o[4] = x2_[0] + lrelu(acc45[0] + bv1.x);
        o[5] = x2_[1] + lrelu(acc45[1] + bv1.y);
        o[6] = x3_[0] + lrelu(acc67[0] + bv1.z);
        o[7] = x3_[1] + lrelu(acc67[1] + bv1.w);
    }

    // stash this node's 8 channels, then block-reduce 8 nodes -> 1 partial row
    #pragma unroll
    for (int c = 0; c < 8; c++) red[node][hl * 8 + c] = o[c];
    __syncthreads();
    int t = tid;
    float sum = 0.f;
    #pragma unroll
    for (int n = 0; n < 8; n++) sum += red[n][t];
    partial[(size_t)blockIdx.x * 256 + t] = sum;
}

// ---------- pooling tail (parallel tree: 16384 -> 512 -> 32 -> 2) + head ----------

__global__ void k_ptree(const float* __restrict__ in, float* __restrict__ out,
                        int rowsPerChunk) {
    int blk = blockIdx.x, t = threadIdx.x;
    size_t rowbase = (size_t)blk * rowsPerChunk;
    float s = 0.f;
    for (int j = 0; j < rowsPerChunk; j++)
        s += in[(rowbase + j) * 256 + t];
    out[(size_t)blk * 256 + t] = s;
}

__global__ void k_pool3(const float* __restrict__ partial2, float* __restrict__ pooled,
                        int chunksPerBatch, float inv) {
    int b = blockIdx.x, t = threadIdx.x;
    float s = 0.f;
    for (int j = 0; j < chunksPerBatch; j++)
        s += partial2[((size_t)b * chunksPerBatch + j) * 256 + t];
    pooled[b * 256 + t] = s * inv;
}

__global__ void k_head(const float* __restrict__ pooled, const float* __restrict__ Wh,
                       const float* __restrict__ bh, float* __restrict__ out) {
    int b = blockIdx.x, o = threadIdx.x;
    float acc = bh[o];
    for (int h = 0; h < H_DIM; h++) acc += pooled[b * H_DIM + h] * Wh[h * OUT_DIM + o];
    out[b * OUT_DIM + o] = acc;
}

// ---------- host ----------

extern "C" void kernel_launch(void* const* d_in, const int* in_sizes, int n_in,
                              void* d_out, int out_size, void* d_ws, size_t ws_size,
                              hipStream_t stream) {
    const float* sst  = (const float*)d_in[0];
    const int*   mask = (const int*)d_in[1];
    const int*   eidx = (const int*)d_in[2];
    const float* W1   = (const float*)d_in[3];
    const float* b1   = (const float*)d_in[4];
    const float* Ws   = (const float*)d_in[5];
    const float* bs   = (const float*)d_in[6];
    const float* Wh   = (const float*)d_in[7];
    const float* bh   = (const float*)d_in[8];

    const int B  = out_size / OUT_DIM;               // 2
    const int Nn = in_sizes[1];                      // 65536
    const int E  = in_sizes[2] / 2;                  // 1048576
    const int F  = in_sizes[0] / B;                  // 686364
    const int DEPTH = in_sizes[5] / (H_DIM * H_DIM); // 8
    const int NT = B * Nn;                           // 131072

    // workspace carve-up (256B aligned) — total ~107 MB
    size_t off = 0;
    char* base = (char*)d_ws;
    auto alloc = [&](size_t bytes) -> void* {
        void* p = base + off;
        off += (bytes + 255) & ~(size_t)255;
        return p;
    };
    unsigned char* xh8     = (unsigned char*)alloc((size_t)NT * 256);   // 33.5 MB fp8 residual
    unsigned char* zbuf    = (unsigned char*)alloc((size_t)NT * 256);   // 33.5 MB fp8
    float*    x0      = (float*)alloc((size_t)NT * 4);
    float*    y0      = (float*)alloc((size_t)NT * 4);
    int*      cnt     = (int*)alloc((size_t)NT * 4);
    int*      startp  = (int*)alloc((size_t)NT * 4);
    float*    dis     = (float*)alloc((size_t)NT * 4);
    int*      bsum    = (int*)alloc(4096);
    int*      bpre    = (int*)alloc(4096);
    int*      rank    = (int*)alloc((size_t)E * 4);                     // 4 MB
    int2*     ecsr    = (int2*)alloc((size_t)E * 8);                    // 8 MB
    ushort_t* Wt      = (ushort_t*)alloc((size_t)DEPTH * H_DIM * H_DIM * 2);  // 1 MB fp16
    float*    partial = (float*)alloc((size_t)(NT / 8) * 256 * 4);      // 16.8 MB
    float*    partialB= (float*)alloc((size_t)512 * 256 * 4);           // 512 KB
    float*    partial2= (float*)alloc((size_t)64 * 256 * 4);
    float*    pooled  = (float*)alloc((size_t)B * 256 * 4);
    if (off > ws_size) return;   // workspace too small: fail visibly

    const int* esrc = eidx;
    const int* edst = eidx + E;

    dim3 blk(256);
    int gNT = (NT + 255) / 256;
    int gE  = (E + 255) / 256;
    int nb  = gNT;               // 512 scan blocks

    hipMemsetAsync(cnt, 0, (size_t)NT * 4, stream);

    k_gather_x0<<<gNT, blk, 0, stream>>>(sst, mask, x0, NT, Nn, F);
    k_count<<<gE, blk, 0, stream>>>(edst, cnt, rank, E);
    k_dis<<<gNT, blk, 0, stream>>>(cnt, dis, NT);
    k_scan_block<<<nb, blk, 0, stream>>>(cnt, bsum, NT);
    k_scan_top<<<1, 512, 0, stream>>>(bsum, bpre, nb);
    k_scan_scatter<<<nb, blk, 0, stream>>>(cnt, bpre, startp, NT);
    k_fill<<<gE, blk, 0, stream>>>(esrc, edst, rank, startp, dis, ecsr, E);
    k_prepW<<<(DEPTH * H_DIM * H_DIM + 255) / 256, blk, 0, stream>>>(Ws, Wt, DEPTH * H_DIM * H_DIM);

    // layer 1: scalar -> H (fp8 residual stream)
    k_agg0<<<gNT, blk, 0, stream>>>(x0, startp, cnt, ecsr, dis, y0, NT);
    k_expand<<<(NT * 64 + 255) / 256, blk, 0, stream>>>(x0, y0, W1, b1,
                                                        (unsigned int*)xh8, NT);

    // layers 2..8: z = xh8@W (fp8 out), then aggregate+bias+leaky+residual into xh8
    for (int l = 0; l < DEPTH - 1; l++) {
        k_gemm<<<512, blk, 0, stream>>>(xh8, Wt + (size_t)l * H_DIM * H_DIM, zbuf, NT);
        k_aggres<<<NT / 8, blk, 0, stream>>>(zbuf, startp, cnt, ecsr, dis,
                                             bs + (size_t)l * H_DIM, xh8, NT);
    }
    // layer 9: fused aggregate + residual + block pooling (no xh write)
    {
        int l = DEPTH - 1;
        k_gemm<<<512, blk, 0, stream>>>(xh8, Wt + (size_t)l * H_DIM * H_DIM, zbuf, NT);
        k_aggres_pool<<<NT / 8, blk, 0, stream>>>(zbuf, startp, cnt, ecsr, dis,
                                                  bs + (size_t)l * H_DIM, xh8, partial, NT);
    }

    // pool tail: 16384 partial rows -> 512 -> 32 -> 2 (all stages parallel)
    int pblocks = NT / 8;                  // 16384
    k_ptree<<<512, blk, 0, stream>>>(partial, partialB, pblocks / 512);     // 32 rows each
    k_ptree<<<32, blk, 0, stream>>>(partialB, partial2, 16);                // 16 rows each
    k_pool3<<<B, blk, 0, stream>>>(partial2, pooled, 32 / B, 1.0f / (float)Nn);
    k_head<<<B, blk, 0, stream>>>(pooled, Wh, bh, (float*)d_out);
}